// Round 26
// baseline (1788.945 us; speedup 1.0000x reference)
//
#include <hip/hip_runtime.h>
#include <hip/hip_bf16.h>
#include <math.h>

#define Bq   256
#define Nimg 196
#define Tseq 26
#define Hd   512
#define H4   2048
#define Ccls 1000
#define KP   1536   // 3*Hd split-K'
#define MT3  19968  // 3 * Bq * Tseq

typedef int   int4v  __attribute__((ext_vector_type(4)));
typedef float f32x4  __attribute__((ext_vector_type(4)));

#define SWZ8(x) ((x) ^ (((x) >> 3) & 7))   // LDS slot swizzle (involution, bits0-2 ^= bits3-5)

// ------------------------------------------------------------ fast activations
__device__ __forceinline__ float fast_tanh(float x) {
    float e = __expf(2.0f * x);
    return 1.0f - 2.0f * __builtin_amdgcn_rcpf(e + 1.0f);
}
__device__ __forceinline__ float fast_sigmoid(float x) {
    return __builtin_amdgcn_rcpf(1.0f + __expf(-x));
}

// ------------------------------------------------------------- bf16 split utils
__device__ __forceinline__ short f2bf(float x) {
    union { float f; unsigned u; } a; a.f = x;
    unsigned r = a.u + 0x7FFF + ((a.u >> 16) & 1);   // RNE
    return (short)(r >> 16);
}
__device__ __forceinline__ float bf2f(short b) {
    union { float f; unsigned u; } a; a.u = ((unsigned)(unsigned short)b) << 16;
    return a.f;
}

// ---------------------------------------------------------------- embed gather
__global__ void embed_kernel(const int* __restrict__ q, const float* __restrict__ table,
                             short* __restrict__ words2) {
    int row = blockIdx.x;               // b*T + t
    int tok = q[row];
    int c4 = threadIdx.x * 4;           // block 128
    float4 v = *reinterpret_cast<const float4*>(table + (size_t)tok * Hd + c4);
    short h0 = f2bf(v.x), h1 = f2bf(v.y), h2 = f2bf(v.z), h3 = f2bf(v.w);
    short l0 = f2bf(v.x - bf2f(h0)), l1 = f2bf(v.y - bf2f(h1));
    short l2 = f2bf(v.z - bf2f(h2)), l3 = f2bf(v.w - bf2f(h3));
    *reinterpret_cast<short4*>(words2 + (size_t)row * 1024 + c4) = make_short4(h0, h1, h2, h3);
    *reinterpret_cast<short4*>(words2 + (size_t)row * 1024 + 512 + c4) = make_short4(l0, l1, l2, l3);
}

// ---- X [M,512] fp32 -> X2 [M,1024] bf16 (hi|lo). grid M/2 x 256
__global__ void split_kernel(const float* __restrict__ X, short* __restrict__ X2) {
    int i4 = blockIdx.x * 256 + threadIdx.x;       // float4 index over M*128
    int m = i4 >> 7, c4 = (i4 & 127) * 4;
    float4 v = *reinterpret_cast<const float4*>(X + ((size_t)m << 9) + c4);
    short h0 = f2bf(v.x), h1 = f2bf(v.y), h2 = f2bf(v.z), h3 = f2bf(v.w);
    short l0 = f2bf(v.x - bf2f(h0)), l1 = f2bf(v.y - bf2f(h1));
    short l2 = f2bf(v.z - bf2f(h2)), l3 = f2bf(v.w - bf2f(h3));
    *reinterpret_cast<short4*>(X2 + (size_t)m * 1024 + c4) = make_short4(h0, h1, h2, h3);
    *reinterpret_cast<short4*>(X2 + (size_t)m * 1024 + 512 + c4) = make_short4(l0, l1, l2, l3);
}

// ---- ALL weight splits in one launch. grid (8, 8, 14), block 256.
// z==1: W_corr ROWS (for Qc = Q @ W_corr^T); all other z: columns (transposed).
__global__ __launch_bounds__(256) void wsplit_all_kernel(
    const float* __restrict__ W_img, const float* __restrict__ W_corr,
    const float* __restrict__ W_ie, const float* __restrict__ W_qe,
    const float* __restrict__ W_uni, const float* __restrict__ W_bi,
    const float* __restrict__ W_tri, const float* __restrict__ lstm_k,
    short* __restrict__ WimgT2, short* __restrict__ WcorrR2,
    short* __restrict__ WieT2, short* __restrict__ WqeT2,
    short* __restrict__ WconvT2, short* __restrict__ lkT2) {
    const int z = blockIdx.z;
    const int tid = threadIdx.x;
    const int k0 = blockIdx.y * 64;
    const size_t HK = (size_t)Hd * KP;
    if (z == 1) {   // rows of W_corr, no transpose
        const int n0 = blockIdx.x * 64;
        const int n = tid >> 2, ksub = (tid & 3) * 16;
        const float* src = W_corr + (size_t)(n0 + n) * Hd + k0 + ksub;
        size_t base = (size_t)(n0 + n) * KP + k0 + ksub;
        #pragma unroll
        for (int k = 0; k < 16; ++k) {
            float x = src[k];
            short h = f2bf(x);
            short l = f2bf(x - bf2f(h));
            WcorrR2[base + k] = h;
            WcorrR2[base + 512 + k] = h;
            WcorrR2[base + 1024 + k] = l;
        }
        return;
    }
    const float* W; short* WT2; int Nw, n0;
    if (z < 10) {
        Nw = Hd; n0 = blockIdx.x * 64;
        switch (z) {
            case 0: W = W_img;  WT2 = WimgT2;  break;
            case 2: W = W_ie;   WT2 = WieT2;   break;
            case 3: W = W_qe;   WT2 = WqeT2;   break;
            case 4: W = W_uni;                     WT2 = WconvT2 + 0 * HK; break;
            case 5: W = W_bi;                      WT2 = WconvT2 + 1 * HK; break;
            case 6: W = W_bi + (size_t)Hd * Hd;    WT2 = WconvT2 + 2 * HK; break;
            case 7: W = W_tri;                     WT2 = WconvT2 + 3 * HK; break;
            case 8: W = W_tri + (size_t)Hd * Hd;   WT2 = WconvT2 + 4 * HK; break;
            default:W = W_tri + 2 * (size_t)Hd * Hd; WT2 = WconvT2 + 5 * HK; break;
        }
    } else {
        Nw = H4; W = lstm_k; WT2 = lkT2;
        n0 = ((z - 10) * 8 + blockIdx.x) * 64;
    }
    __shared__ float tile[64][65];
    #pragma unroll
    for (int p = 0; p < 16; ++p) {
        int r = p * 4 + (tid >> 6);
        int c = tid & 63;
        tile[r][c] = W[(size_t)(k0 + r) * Nw + n0 + c];
    }
    __syncthreads();
    const int n = tid >> 2;
    const int ksub = (tid & 3) * 16;
    size_t base = (size_t)(n0 + n) * KP + k0 + ksub;
    #pragma unroll
    for (int k = 0; k < 16; ++k) {
        float x = tile[ksub + k][n];
        short h = f2bf(x);
        short l = f2bf(x - bf2f(h));
        WT2[base + k] = h;
        WT2[base + 512 + k] = h;
        WT2[base + 1024 + k] = l;
    }
}

// ---- qb[r] = Q[r,:] . b_corr  (split-bf16 Q rows). grid MT3/4, block 256
__global__ __launch_bounds__(256) void qb_kernel(const short* __restrict__ Q2,
                                                 const float* __restrict__ b_corr,
                                                 float* __restrict__ qb) {
    const int tid = threadIdx.x, lane = tid & 63, wid = tid >> 6;
    const int r = blockIdx.x * 4 + wid;
    const short* row = Q2 + (size_t)r * 1024 + lane * 8;
    float v = 0.f;
    #pragma unroll
    for (int k = 0; k < 8; ++k) {
        float x = bf2f(row[k]) + bf2f(row[512 + k]);
        v += x * b_corr[lane * 8 + k];
    }
    #pragma unroll
    for (int off = 32; off; off >>= 1) v += __shfl_xor(v, off);
    if (lane == 0) qb[r] = v;
}

// -------------------------------------------------- split-bf16 MFMA GEMM
__device__ __forceinline__ void mfma16(f32x4& acc, int4v a, int4v b) {
    asm volatile("v_mfma_f32_16x16x32_bf16 %0, %1, %2, %0" : "+v"(acc) : "v"(a), "v"(b));
}

// ===================== 8-phase 256x256 tile, BK=64, 8 waves, counted vmcnt =====================
// R21 schedule (spread STAGE across phases, vmcnt(2)) + 1D grid with bijective XCD chunking.
// OUT: 0 fp32 C; 1 split-bf16 C2; 2 MIXED (col<512 -> split C2 no bias, col>=512 -> fp32 C+bias).
// Requires M%256==0, N%256==0. Accumulation order identical across variants (32-k chunks asc).
template <int ACT, int OUT>
__global__ __launch_bounds__(512) void mfma_gemm8_kernel(
    const short* __restrict__ A2, const short* __restrict__ W2T,
    const float* __restrict__ bias, float* __restrict__ C, short* __restrict__ C2,
    int M, int N) {
    __shared__ __align__(16) short L[2][2][4][4096];  // [slot][A/B][h*2+kh][512 slots * 8]
    const int tid = threadIdx.x;
    const int lane = tid & 63, wid = tid >> 6;
    // bijective chunked XCD swizzle (m204): XCD k gets a contiguous chunk of logical IDs
    const int Cn = N >> 8;
    const int nwg = (M >> 8) * Cn;
    int Lb = blockIdx.x;
    int xcd = Lb & 7, lq = Lb >> 3;
    int q8 = nwg >> 3, r8 = nwg & 7;
    int logical = (xcd < r8 ? xcd * (q8 + 1) : r8 * (q8 + 1) + (xcd - r8) * q8) + lq;
    const int row0 = (logical / Cn) << 8, col0 = (logical % Cn) << 8;
    const int wm = wid >> 2, wn = wid & 3;    // 2M x 4N waves; per-wave out 128x64
    // staging decode (identical scheme to proven 2-phase kernel, 512 slots/sub-block)
    const int sdec = SWZ8(tid);
    const int frs = sdec >> 6, rs = (sdec >> 2) & 15, kb = sdec & 3;
    const int koff = kb * 8;
    const int aro = frs * 16 + rs;            // 0..127 row within half
    const short* aptr[2]; const short* bptr[2];
    aptr[0] = A2 + (size_t)(row0 + aro) * 1024;
    aptr[1] = A2 + (size_t)(row0 + 128 + aro) * 1024;
    bptr[0] = W2T + (size_t)(col0 + aro) * KP;
    bptr[1] = W2T + (size_t)(col0 + 128 + aro) * KP;
    const int ldso = wid * 64 * 8;            // wave-uniform dest base within sub-block
    auto STAGE = [&](int slot, int tile, int p) {
        int h = p & 1, kh = p >> 1;
        int kk = tile * 64 + kh * 32 + koff;
        int ka = kk >= 1024 ? kk - 1024 : kk;   // A wrap: hi|lo|hi
        __builtin_amdgcn_global_load_lds(
            (const __attribute__((address_space(1))) void*)(aptr[h] + ka),
            (__attribute__((address_space(3))) void*)(&L[slot][0][h * 2 + kh][ldso]),
            16, 0, 0);
        __builtin_amdgcn_global_load_lds(
            (const __attribute__((address_space(1))) void*)(bptr[h] + kk),
            (__attribute__((address_space(3))) void*)(&L[slot][1][h * 2 + kh][ldso]),
            16, 0, 0);
    };
    f32x4 acc[8][4] = {};
    #pragma unroll
    for (int p = 0; p < 4; ++p) STAGE(0, 0, p);   // prologue: tile 0 (8 loads)
    const int NT = KP / 64;   // 24
    for (int t = 0; t < NT; ++t) {
        const int sl = t & 1;
        int4v bfr[4][2];
        #pragma unroll
        for (int p = 0; p < 4; ++p) {
            if (p == 0) {
                if (t + 1 < NT) {
                    STAGE(sl ^ 1, t + 1, 0);
                    asm volatile("s_waitcnt vmcnt(2)" ::: "memory");  // tile t's 8 landed (mine)
                } else {
                    asm volatile("s_waitcnt vmcnt(0)" ::: "memory");
                }
                __builtin_amdgcn_s_barrier();       // everyone's tile-t loads landed
                __builtin_amdgcn_sched_barrier(0);
                #pragma unroll
                for (int nf = 0; nf < 4; ++nf)
                    #pragma unroll
                    for (int kh = 0; kh < 2; ++kh) {
                        int off = ((wn & 1) * 4 + nf) * 64 + (lane & 15) * 4 + (lane >> 4);
                        bfr[nf][kh] = *reinterpret_cast<const int4v*>(
                            &L[sl][1][(wn >> 1) * 2 + kh][SWZ8(off) * 8]);
                    }
            } else {
                if (t + 1 < NT) STAGE(sl ^ 1, t + 1, p);
            }
            int4v af[2][2];
            #pragma unroll
            for (int i = 0; i < 2; ++i)
                #pragma unroll
                for (int kh = 0; kh < 2; ++kh) {
                    int off = (p * 2 + i) * 64 + (lane & 15) * 4 + (lane >> 4);
                    af[i][kh] = *reinterpret_cast<const int4v*>(
                        &L[sl][0][wm * 2 + kh][SWZ8(off) * 8]);
                }
            __builtin_amdgcn_s_setprio(1);
            #pragma unroll
            for (int i = 0; i < 2; ++i)
                #pragma unroll
                for (int nf = 0; nf < 4; ++nf)
                    #pragma unroll
                    for (int kh = 0; kh < 2; ++kh)
                        mfma16(acc[p * 2 + i][nf], af[i][kh], bfr[nf][kh]);
            __builtin_amdgcn_s_setprio(0);
        }
        asm volatile("s_waitcnt lgkmcnt(0)" ::: "memory");  // my reads of slot sl done
        __builtin_amdgcn_s_barrier();                        // all waves done reading sl
        __builtin_amdgcn_sched_barrier(0);                   // next iter's STAGE may not cross
    }
    asm volatile("s_nop 7\n\ts_nop 7" ::: "memory");   // MFMA->VALU read hazard
    #pragma unroll
    for (int mf = 0; mf < 8; ++mf) {
        #pragma unroll
        for (int nf = 0; nf < 4; ++nf) {
            int col = col0 + wn * 64 + nf * 16 + (lane & 15);
            float bv;
            if (OUT == 2) bv = (col >= 512) ? bias[col - 512] : 0.f;
            else bv = bias ? bias[col] : 0.f;
            #pragma unroll
            for (int r = 0; r < 4; ++r) {
                int row = row0 + wm * 128 + mf * 16 + (lane >> 4) * 4 + r;
                float v = acc[mf][nf][r] + bv;
                if (ACT == 1) v = fast_tanh(v);
                if (OUT == 0) {
                    C[(size_t)row * N + col] = v;
                } else if (OUT == 1) {
                    short h = f2bf(v), l = f2bf(v - bf2f(h));
                    C2[(size_t)row * 1024 + col] = h;
                    C2[(size_t)row * 1024 + 512 + col] = l;
                } else {   // OUT == 2: mixed Qc|qe
                    if (col < 512) {
                        short h = f2bf(v), l = f2bf(v - bf2f(h));
                        C2[(size_t)row * 1024 + col] = h;
                        C2[(size_t)row * 1024 + 512 + col] = l;
                    } else {
                        C[(size_t)row * Hd + (col - 512)] = v;
                    }
                }
            }
        }
    }
}

// ----------------- batched MFMA: wm[lvl,b] = tanh(Qc[lvl,b] (26x512) @ img[b]^T + qb)
__global__ __launch_bounds__(256) void wm3_mfma_kernel(
    const short* __restrict__ Qc2, const short* __restrict__ img2,
    const float* __restrict__ qb, float* __restrict__ wm0, float* __restrict__ wm1,
    float* __restrict__ wm2) {
    __shared__ __align__(16) short Asl[2][4096];
    __shared__ __align__(16) short Bsl[2][4096];
    const int tid = threadIdx.x;
    const int lane = tid & 63, wid = tid >> 6;
    const int col0 = blockIdx.x * 128;       // n-tile
    const int b = blockIdx.y;
    const int wmq = wid >> 1, wn = wid & 1;
    const short* ab[2]; const short* bb[2]; int koff[2];
    #pragma unroll
    for (int c = 0; c < 2; ++c) {
        int d = c * 256 + tid;
        int s = SWZ8(d);
        int fr = s >> 6, r = (s >> 2) & 15, kb = s & 3;
        koff[c] = kb * 8;
        int arow = fr * 16 + r;
        int lvl = arow / 26, at = arow - lvl * 26;
        if (arow >= 78) { lvl = 0; at = 0; }
        ab[c] = Qc2 + ((size_t)lvl * (Bq * Tseq) + (size_t)(b * 26 + at)) * 1024;
        int brow = col0 + fr * 16 + r;
        if (brow > 195) brow = 195;
        bb[c] = img2 + ((size_t)(b * 196 + brow)) * 1024;
    }
    auto STAGE = [&](int buf, int k0) {
        #pragma unroll
        for (int c = 0; c < 2; ++c) {
            int kk = k0 + koff[c];
            int ka = kk >= 1024 ? kk - 1024 : kk;      // A: hi|lo|hi
            int kbv = kk >= 512 ? kk - 512 : kk;       // B: hi|hi|lo
            __builtin_amdgcn_global_load_lds(
                (const __attribute__((address_space(1))) void*)(ab[c] + ka),
                (__attribute__((address_space(3))) void*)(&Asl[buf][(c * 256 + wid * 64) * 8]),
                16, 0, 0);
            __builtin_amdgcn_global_load_lds(
                (const __attribute__((address_space(1))) void*)(bb[c] + kbv),
                (__attribute__((address_space(3))) void*)(&Bsl[buf][(c * 256 + wid * 64) * 8]),
                16, 0, 0);
        }
    };
    f32x4 acc[4][4] = {};
    STAGE(0, 0);
    int cur = 0;
    for (int k0 = 0; k0 < KP; k0 += 32) {
        if (k0 + 32 < KP) {
            STAGE(cur ^ 1, k0 + 32);
            asm volatile("s_waitcnt vmcnt(4)" ::: "memory");
        } else {
            asm volatile("s_waitcnt vmcnt(0)" ::: "memory");
        }
        __builtin_amdgcn_s_barrier();
        __builtin_amdgcn_sched_barrier(0);
        int4v af[4], bfr[4];
        #pragma unroll
        for (int f = 0; f < 4; ++f) {
            int sa = (wmq * 4 + f) * 64 + (lane & 15) * 4 + (lane >> 4);
            af[f] = *reinterpret_cast<const int4v*>(&Asl[cur][SWZ8(sa) * 8]);
            int sb = (wn * 4 + f) * 64 + (lane & 15) * 4 + (lane >> 4);
            bfr[f] = *reinterpret_cast<const int4v*>(&Bsl[cur][SWZ8(sb) * 8]);
        }
        #pragma unroll
        for (int i = 0; i < 4; ++i)
            #pragma unroll
            for (int j = 0; j < 4; ++j)
                mfma16(acc[i][j], af[i], bfr[j]);
        asm volatile("s_waitcnt lgkmcnt(0)" ::: "memory");
        __builtin_amdgcn_s_barrier();
        __builtin_amdgcn_sched_barrier(0);
        cur ^= 1;
    }
    asm volatile("s_nop 7\n\ts_nop 7" ::: "memory");
    #pragma unroll
    for (int i = 0; i < 4; ++i) {
        #pragma unroll
        for (int j = 0; j < 4; ++j) {
            int col = col0 + wn * 64 + j * 16 + (lane & 15);
            if (col >= Nimg) continue;
            #pragma unroll
            for (int r = 0; r < 4; ++r) {
                int row = wmq * 64 + i * 16 + (lane >> 4) * 4 + r;
                if (row >= 78) continue;
                int lvl = row / 26, t = row - lvl * 26;
                float* dst = (lvl == 0) ? wm0 : (lvl == 1) ? wm1 : wm2;
                float qbv = qb[(size_t)lvl * (Bq * Tseq) + b * 26 + t];
                dst[((size_t)(b * 26 + t)) * Nimg + col] = fast_tanh(acc[i][j][r] + qbv);
            }
        }
    }
}

// ---- conv tap-combine
__global__ void conv_combine_kernel(const float* __restrict__ Y,
                                    const float* __restrict__ bu, const float* __restrict__ bb,
                                    const float* __restrict__ bt,
                                    short* __restrict__ phrase2) {
    int idx = blockIdx.x * 256 + threadIdx.x;      // over MT*512
    int m = idx >> 9, c = idx & 511;
    int t = m % Tseq;
    const float* Ym = Y + (size_t)m * 3072;
    float u = Ym[c] + bu[c];
    float bv = bb[c];
    if (t > 0)  bv += Ym[-3072 + 512 + c];
    if (t < 25) bv += Ym[3072 + 1024 + c];
    float tv = Ym[2048 + c] + bt[c];
    if (t > 1)  tv += Ym[-6144 + 1536 + c];
    if (t < 24) tv += Ym[6144 + 2560 + c];
    float ph = fast_tanh(fmaxf(fmaxf(fast_tanh(u), fast_tanh(bv)), fast_tanh(tv)));
    short h = f2bf(ph), l = f2bf(ph - bf2f(h));
    phrase2[(size_t)m * 1024 + c] = h;
    phrase2[(size_t)m * 1024 + 512 + c] = l;
}

// ---------------------------------------------------------------- head GEMM
template <int ACT>  // 0 none, 1 tanh, 2 relu
__global__ __launch_bounds__(256) void gemm_kernel(
    const float* __restrict__ A, int lda,
    const float* __restrict__ W, int ldw,
    const float* __restrict__ bias,
    float* __restrict__ C, int ldc,
    int M, int Ncols, int K) {
    __shared__ float As[16][68];
    __shared__ float Ws[16][68];
    const int tid = threadIdx.x;
    const int tx4 = (tid & 15) * 4, ty4 = (tid >> 4) * 4;
    const int row0 = blockIdx.y * 64, col0 = blockIdx.x * 64;
    const int am = tid >> 2, ak = (tid & 3) * 4;
    const int wk = tid >> 4, wc = (tid & 15) * 4;
    float acc[4][4] = {};
    for (int k0 = 0; k0 < K; k0 += 16) {
        {
            int gr = row0 + am;
            float4 v = make_float4(0.f, 0.f, 0.f, 0.f);
            if (gr < M) v = *reinterpret_cast<const float4*>(A + (size_t)gr * lda + k0 + ak);
            As[ak + 0][am] = v.x; As[ak + 1][am] = v.y; As[ak + 2][am] = v.z; As[ak + 3][am] = v.w;
        }
        {
            int gc = col0 + wc;
            const float* wp = W + (size_t)(k0 + wk) * ldw + gc;
            float4 v = make_float4(0.f, 0.f, 0.f, 0.f);
            if (gc + 3 < Ncols) v = *reinterpret_cast<const float4*>(wp);
            else {
                if (gc + 0 < Ncols) v.x = wp[0];
                if (gc + 1 < Ncols) v.y = wp[1];
                if (gc + 2 < Ncols) v.z = wp[2];
                if (gc + 3 < Ncols) v.w = wp[3];
            }
            Ws[wk][wc + 0] = v.x; Ws[wk][wc + 1] = v.y; Ws[wk][wc + 2] = v.z; Ws[wk][wc + 3] = v.w;
        }
        __syncthreads();
        #pragma unroll 4
        for (int kk = 0; kk < 16; ++kk) {
            float4 a4 = *reinterpret_cast<const float4*>(&As[kk][ty4]);
            float4 b4 = *reinterpret_cast<const float4*>(&Ws[kk][tx4]);
            float a[4] = {a4.x, a4.y, a4.z, a4.w};
            float b[4] = {b4.x, b4.y, b4.z, b4.w};
            #pragma unroll
            for (int i = 0; i < 4; ++i)
                #pragma unroll
                for (int j = 0; j < 4; ++j) acc[i][j] += a[i] * b[j];
        }
        __syncthreads();
    }
    #pragma unroll
    for (int i = 0; i < 4; ++i) {
        int r = row0 + ty4 + i;
        if (r >= M) continue;
        #pragma unroll
        for (int j = 0; j < 4; ++j) {
            int c = col0 + tx4 + j;
            if (c >= Ncols) continue;
            float v = acc[i][j];
            if (bias) v += bias[c];
            if (ACT == 1) v = fast_tanh(v);
            else if (ACT == 2) v = fmaxf(v, 0.f);
            C[(size_t)r * ldc + c] = v;
        }
    }
}

// ------------------------------------------------- LSTM: split-K GEMM + gates
__global__ __launch_bounds__(256) void lstm_gemm_kernel(
    const float* __restrict__ h, const float* __restrict__ rk, float* __restrict__ zgp) {
    __shared__ float As[16][68];
    __shared__ float Ws[16][68];
    const int tid = threadIdx.x;
    const int tx4 = (tid & 15) * 4, ty4 = (tid >> 4) * 4;
    const int col0 = blockIdx.x * 64, row0 = blockIdx.y * 64, kb = blockIdx.z * 256;
    const int am = tid >> 2, ak = (tid & 3) * 4;
    const int wk = tid >> 4, wc = (tid & 15) * 4;
    float acc[4][4] = {};
    for (int k0 = kb; k0 < kb + 256; k0 += 16) {
        {
            float4 v = *reinterpret_cast<const float4*>(h + (size_t)(row0 + am) * Hd + k0 + ak);
            As[ak + 0][am] = v.x; As[ak + 1][am] = v.y; As[ak + 2][am] = v.z; As[ak + 3][am] = v.w;
        }
        {
            *reinterpret_cast<float4*>(&Ws[wk][wc]) =
                *reinterpret_cast<const float4*>(rk + (size_t)(k0 + wk) * H4 + col0 + wc);
        }
        __syncthreads();
        #pragma unroll 4
        for (int kk = 0; kk < 16; ++kk) {
            float4 a4 = *reinterpret_cast<const float4*>(&As[kk][ty4]);
            float4 b4 = *reinterpret_cast<const float4*>(&Ws[kk][tx4]);
            float a[4] = {a4.x, a4.y, a4.z, a4.w};
            float b[4] = {b4.x, b4.y, b4.z, b4.w};
            #pragma unroll
            for (int i = 0; i < 4; ++i)
                #pragma unroll
                for (int j = 0; j < 4; ++j) acc[i][j] += a[i] * b[j];
        }
        __syncthreads();
    }
    float* dst = zgp + (size_t)blockIdx.z * (Bq * H4);
    #pragma unroll
    for (int i = 0; i < 4; ++i) {
        int r = row0 + ty4 + i;
        *reinterpret_cast<float4*>(dst + (size_t)r * H4 + col0 + tx4) =
            make_float4(acc[i][0], acc[i][1], acc[i][2], acc[i][3]);
    }
}

__global__ __launch_bounds__(256) void lstm_gates_kernel(
    const float* __restrict__ zgp, const float* __restrict__ xp,
    float* __restrict__ c, float* __restrict__ h, short* __restrict__ sent2, int t) {
    int i = blockIdx.x * 256 + threadIdx.x;  // B*H
    int b = i >> 9, hh = i & 511;
    const float* xr = xp + ((size_t)b * Tseq + t) * H4;
    float z[4];
    #pragma unroll
    for (int g = 0; g < 4; ++g) {
        float s = xr[g * 512 + hh];
        #pragma unroll
        for (int kc = 0; kc < 2; ++kc)
            s += zgp[(size_t)kc * (Bq * H4) + (size_t)b * H4 + g * 512 + hh];
        z[g] = s;
    }
    float ig = fast_sigmoid(z[0]);
    float fg = fast_sigmoid(z[1]);
    float gg = fast_tanh(z[2]);
    float og = fast_sigmoid(z[3]);
    float cv = fg * c[i] + ig * gg;
    c[i] = cv;
    float hv = og * fast_tanh(cv);
    h[i] = hv;
    short hb = f2bf(hv), lb = f2bf(hv - bf2f(hb));
    sent2[((size_t)b * Tseq + t) * 1024 + hh] = hb;
    sent2[((size_t)b * Tseq + t) * 1024 + 512 + hh] = lb;
}

// ---- fused qlog for all 3 calls; 2 h-chunks of 256, 2 h per thread
__global__ __launch_bounds__(256) void qlog3_kernel(
    const float* __restrict__ wm0, const float* __restrict__ wm1, const float* __restrict__ wm2,
    const float* __restrict__ Ie, const float* __restrict__ qe0, const float* __restrict__ qe1,
    const float* __restrict__ qe2, const float* __restrict__ wqa, float* __restrict__ qlogp) {
    const int b = blockIdx.x, chunk = blockIdx.y;   // chunk in {0,1}
    __shared__ float wms[3][Tseq][Nimg];
    __shared__ float red[4][40];
    const int tid = threadIdx.x;
    const float* wsrc[3] = {wm0, wm1, wm2};
    for (int e = tid; e < 3 * 1274; e += 256) {
        int c = e / 1274, r = e % 1274;
        *reinterpret_cast<float4*>(&wms[c][0][0] + 4 * r) =
            *reinterpret_cast<const float4*>(wsrc[c] + (size_t)b * (Tseq * Nimg) + 4 * r);
    }
    __syncthreads();
    const int hl = tid & 127, thalf = tid >> 7, tt0 = thalf * 13;
    const int h1 = chunk * 256 + hl, h2 = h1 + 128;
    float acc[3][13][2] = {};
    const float* iep1 = Ie + (size_t)b * Nimg * Hd + h1;
    const float* iep2 = Ie + (size_t)b * Nimg * Hd + h2;
    for (int n4 = 0; n4 < 49; ++n4) {
        float ieA0 = iep1[(size_t)(4 * n4 + 0) * Hd];
        float ieA1 = iep1[(size_t)(4 * n4 + 1) * Hd];
        float ieA2 = iep1[(size_t)(4 * n4 + 2) * Hd];
        float ieA3 = iep1[(size_t)(4 * n4 + 3) * Hd];
        float ieB0 = iep2[(size_t)(4 * n4 + 0) * Hd];
        float ieB1 = iep2[(size_t)(4 * n4 + 1) * Hd];
        float ieB2 = iep2[(size_t)(4 * n4 + 2) * Hd];
        float ieB3 = iep2[(size_t)(4 * n4 + 3) * Hd];
        #pragma unroll
        for (int c = 0; c < 3; ++c)
            #pragma unroll
            for (int tt = 0; tt < 13; ++tt) {
                float4 w4 = *reinterpret_cast<const float4*>(&wms[c][tt0 + tt][4 * n4]);
                acc[c][tt][0] += w4.x * ieA0 + w4.y * ieA1 + w4.z * ieA2 + w4.w * ieA3;
                acc[c][tt][1] += w4.x * ieB0 + w4.y * ieB1 + w4.z * ieB2 + w4.w * ieB3;
            }
    }
    const float wq1 = wqa[h1], wq2 = wqa[h2];
    const int lane = tid & 63, w = tid >> 6;
    const float* qes[3] = {qe0, qe1, qe2};
    #pragma unroll
    for (int c = 0; c < 3; ++c)
        #pragma unroll
        for (int tt = 0; tt < 13; ++tt) {
            int t = tt0 + tt;
            const float* qrow = qes[c] + ((size_t)(b * 26 + t)) * Hd;
            float v = fast_tanh(acc[c][tt][0] + qrow[h1]) * wq1 +
                      fast_tanh(acc[c][tt][1] + qrow[h2]) * wq2;
            #pragma unroll
            for (int off = 32; off; off >>= 1) v += __shfl_xor(v, off);
            if (lane == 0) red[w][c * 13 + tt] = v;
        }
    __syncthreads();
    if (tid < 39) {
        int c = tid / 13, tt = tid % 13;
        qlogp[((size_t)c * Bq + b) * (2 * 26) + chunk * 26 + tt] = red[0][tid] + red[1][tid];
    } else if (tid >= 64 && tid < 103) {
        int id = tid - 64;
        int c = id / 13, tt = id % 13;
        qlogp[((size_t)c * Bq + b) * (2 * 26) + chunk * 26 + 13 + tt] = red[2][id] + red[3][id];
    }
}

// ---- ilog, h-split x2: grid (Bq, 4, 3); t-outer in TWO register-sized passes (<=4 groups each)
__global__ __launch_bounds__(256) void ilog3_kernel(
    const float* __restrict__ wmb, const float* __restrict__ qeb,
    const float* __restrict__ Ie, const float* __restrict__ wia,
    float* __restrict__ ilogp) {
    const int b = blockIdx.x, lvl = blockIdx.z;
    const int nbase = (blockIdx.y & 1) * 98, hc = blockIdx.y >> 1;
    const int hbase = hc * 256;
    const float* wm = wmb + (size_t)lvl * Bq * Tseq * Nimg;
    const float* qe = qeb + (size_t)lvl * Bq * Tseq * Hd;
    float* ilog = ilogp + (size_t)hc * (3 * Bq * Nimg) + (size_t)lvl * Bq * Nimg;
    __shared__ float qes[Tseq][260];
    __shared__ __align__(16) float wms[Tseq][104];
    const int tid = threadIdx.x;
    for (int e = tid; e < Tseq * 64; e += 256) {
        int t = e >> 6, q4 = (e & 63) * 4;
        *reinterpret_cast<float4*>(&qes[t][q4]) =
            *reinterpret_cast<const float4*>(qe + ((size_t)(b * 26 + t)) * Hd + hbase + q4);
    }
    for (int e = tid; e < Tseq * 100; e += 256) {
        int t = e / 100, n = e % 100;
        wms[t][n] = (n < 98 && nbase + n < Nimg)
                    ? wm[((size_t)(b * 26 + t)) * Nimg + nbase + n] : 0.f;
    }
    __syncthreads();
    const int lane = tid & 63, w = tid >> 6;
    const int nw0 = w * 4;
    float4 wi = *reinterpret_cast<const float4*>(wia + hbase + 4 * lane);
    // one pass over t with NG (<=4) accumulator groups starting at group gbeg
    auto PASS = [&](int gbeg, int NG) {
        float4 acc[4][4];
        #pragma unroll
        for (int g = 0; g < 4; ++g)
            #pragma unroll
            for (int i = 0; i < 4; ++i) acc[g][i] = make_float4(0.f, 0.f, 0.f, 0.f);
        for (int t = 0; t < Tseq; ++t) {
            float4 q0 = *reinterpret_cast<const float4*>(&qes[t][4 * lane]);
            #pragma unroll
            for (int g = 0; g < 4; ++g) {
                if (g >= NG) continue;
                int n0 = nw0 + (gbeg + g) * 16;
                if (n0 < 98) {
                    float4 wv = *reinterpret_cast<const float4*>(&wms[t][n0]);
                    float wvv[4] = {wv.x, wv.y, wv.z, wv.w};
                    #pragma unroll
                    for (int i = 0; i < 4; ++i) {
                        acc[g][i].x += wvv[i] * q0.x; acc[g][i].y += wvv[i] * q0.y;
                        acc[g][i].z += wvv[i] * q0.z; acc[g][i].w += wvv[i] * q0.w;
                    }
                }
            }
        }
        #pragma unroll
        for (int g = 0; g < 4; ++g) {
            if (g >= NG) continue;
            int n0 = nw0 + (gbeg + g) * 16;
            if (n0 >= 98) continue;
            #pragma unroll
            for (int i = 0; i < 4; ++i) {
                int n = n0 + i;
                if (n >= 98 || nbase + n >= Nimg) continue;
                const float* iebn = Ie + ((size_t)(b * Nimg) + nbase + n) * Hd + hbase;
                float4 e0 = *reinterpret_cast<const float4*>(iebn + 4 * lane);
                float v = fast_tanh(acc[g][i].x + e0.x) * wi.x +
                          fast_tanh(acc[g][i].y + e0.y) * wi.y +
                          fast_tanh(acc[g][i].z + e0.z) * wi.z +
                          fast_tanh(acc[g][i].w + e0.w) * wi.w;
                #pragma unroll
                for (int off = 32; off; off >>= 1) v += __shfl_xor(v, off);
                if (lane == 0) ilog[(size_t)b * Nimg + nbase + n] = v;
            }
        }
    };
    PASS(0, 4);
    PASS(4, 3);
}

// ---------------------------------------------------------------- softmaxes
// grid (Bq, 3)
__global__ void softmaxT_part_kernel(const float* __restrict__ lgp, float* __restrict__ att) {
    int b = blockIdx.x, c = blockIdx.y, lane = threadIdx.x;  // block 64
    float v = -INFINITY;
    if (lane < Tseq) {
        const float* p = lgp + ((size_t)c * Bq + b) * (2 * 26) + lane;
        v = p[0] + p[26];
    }
    float m = v;
    #pragma unroll
    for (int off = 32; off; off >>= 1) m = fmaxf(m, __shfl_xor(m, off));
    float e = (lane < Tseq) ? __expf(v - m) : 0.f;
    float s = e;
    #pragma unroll
    for (int off = 32; off; off >>= 1) s += __shfl_xor(s, off);
    if (lane < Tseq) att[((size_t)c * Bq + b) * Tseq + lane] = e / s;
}

// grid (Bq, 3); sums the two h-half partials while loading
__global__ void softmax_N_kernel(const float* __restrict__ lg, float* __restrict__ att) {
    int b = blockIdx.x, c = blockIdx.y, lane = threadIdx.x;  // block 64
    const float* lb0 = lg + ((size_t)c * Bq + b) * Nimg;
    const float* lb1 = lb0 + (size_t)3 * Bq * Nimg;
    float* ab = att + ((size_t)c * Bq + b) * Nimg;
    float v[4]; float m = -INFINITY;
    #pragma unroll
    for (int k = 0; k < 4; ++k) {
        int n = lane + 64 * k;
        v[k] = (n < Nimg) ? (lb0[n] + lb1[n]) : -INFINITY;
        m = fmaxf(m, v[k]);
    }
    #pragma unroll
    for (int off = 32; off; off >>= 1) m = fmaxf(m, __shfl_xor(m, off));
    float e[4]; float s = 0.f;
    #pragma unroll
    for (int k = 0; k < 4; ++k) {
        int n = lane + 64 * k;
        e[k] = (n < Nimg) ? __expf(v[k] - m) : 0.f;
        s += e[k];
    }
    #pragma unroll
    for (int off = 32; off; off >>= 1) s += __shfl_xor(s, off);
    #pragma unroll
    for (int k = 0; k < 4; ++k) {
        int n = lane + 64 * k;
        if (n < Nimg) ab[n] = e[k] / s;
    }
}

// ---- fused feature pooling for all 3 calls (split-bf16 inputs reconstructed)
__global__ __launch_bounds__(256) void feat3_kernel(
    const float* __restrict__ qatt0, const float* __restrict__ qatt1, const float* __restrict__ qatt2,
    const float* __restrict__ iatt0, const float* __restrict__ iatt1, const float* __restrict__ iatt2,
    const short* __restrict__ Qw2, const short* __restrict__ Qp2, const short* __restrict__ Qs2,
    const short* __restrict__ img2, float* __restrict__ s_part) {
    const int b = blockIdx.x, chunk = blockIdx.y, tid = threadIdx.x;
    float a[3][2] = {};
    if (chunk == 0) {
        for (int t = 0; t < Tseq; ++t) {
            float w0 = qatt0[b * Tseq + t], w1 = qatt1[b * Tseq + t], w2 = qatt2[b * Tseq + t];
            const short* p0 = Qw2 + ((size_t)(b * Tseq + t)) * 1024;
            const short* p1 = Qp2 + ((size_t)(b * Tseq + t)) * 1024;
            const short* p2 = Qs2 + ((size_t)(b * Tseq + t)) * 1024;
            a[0][0] += w0 * (bf2f(p0[tid]) + bf2f(p0[512 + tid]));
            a[0][1] += w0 * (bf2f(p0[256 + tid]) + bf2f(p0[768 + tid]));
            a[1][0] += w1 * (bf2f(p1[tid]) + bf2f(p1[512 + tid]));
            a[1][1] += w1 * (bf2f(p1[256 + tid]) + bf2f(p1[768 + tid]));
            a[2][0] += w2 * (bf2f(p2[tid]) + bf2f(p2[512 + tid]));
            a[2][1] += w2 * (bf2f(p2[256 + tid]) + bf2f(p2[768 + tid]));
        }
    }
    int ns, ne;
    if (chunk == 0)      { ns = 0;   ne = 30;  }
    else if (chunk == 1) { ns = 30;  ne = 86;  }
    else if (chunk == 2) { ns = 86;  ne = 141; }
    else                 { ns = 141; ne = 196; }
    for (int n = ns; n < ne; ++n) {
        float w0 = iatt0[b * Nimg + n], w1 = iatt1[b * Nimg + n], w2 = iatt2[b * Nimg + n];
        const short* p = img2 + ((size_t)(b * Nimg) + n) * 1024;
        float v0 = bf2f(p[tid]) + bf2f(p[512 + tid]);
        float v1 = bf2f(p[256 + tid]) + bf2f(p[768 + tid]);
        a[0][0] += w0 * v0; a[0][1] += w0 * v1;
        a[1][0] += w1 * v0; a[1][1] += w1 * v1;
        a[2][0] += w2 * v0; a[2][1] += w2 * v1;
    }
    #pragma unroll
    for (int c = 0; c < 3; ++c) {
        float* dst = s_part + ((size_t)(chunk * 3 + c) * Bq + b) * Hd;
        dst[tid] = a[c][0];
        dst[tid + 256] = a[c][1];
    }
}

__global__ void feat_combine_kernel(const float* __restrict__ s_part, float* __restrict__ s0,
                                    float* __restrict__ s1, float* __restrict__ s2) {
    int i = blockIdx.x * 256 + threadIdx.x;  // over 3*Bq*Hd
    int c = i / (Bq * Hd), r = i % (Bq * Hd);
    float v = 0.f;
    #pragma unroll
    for (int ch = 0; ch < 4; ++ch) v += s_part[(size_t)(ch * 3 + c) * (Bq * Hd) + r];
    float* dst = (c == 0) ? s0 : (c == 1) ? s1 : s2;
    dst[r] = v;
}

__global__ void concat_kernel(const float* __restrict__ x, const float* __restrict__ y,
                              float* __restrict__ out) {
    int i = blockIdx.x * 256 + threadIdx.x;  // over B*512
    int b = i >> 9, j = i & 511;
    out[(size_t)b * 1024 + j] = x[i];
    out[(size_t)b * 1024 + 512 + j] = y[i];
}

__global__ __launch_bounds__(256) void softmax_C_kernel(const float* __restrict__ lg,
                                                        float* __restrict__ out) {
    int b = blockIdx.x, tid = threadIdx.x;
    __shared__ float red[4];
    const float* lb = lg + (size_t)b * Ccls;
    float v[4]; float m = -INFINITY;
    #pragma unroll
    for (int k = 0; k < 4; ++k) {
        int j = tid + 256 * k;
        v[k] = (j < Ccls) ? lb[j] : -INFINITY;
        m = fmaxf(m, v[k]);
    }
    #pragma unroll
    for (int off = 32; off; off >>= 1) m = fmaxf(m, __shfl_xor(m, off));
    int lane = tid & 63, w = tid >> 6;
    if (lane == 0) red[w] = m;
    __syncthreads();
    m = fmaxf(fmaxf(red[0], red[1]), fmaxf(red[2], red[3]));
    __syncthreads();
    float e[4]; float s = 0.f;
    #pragma unroll
    for (int k = 0; k < 4; ++k) {
        int j = tid + 256 * k;
        e[k] = (j < Ccls) ? __expf(v[k] - m) : 0.f;
        s += e[k];
    }
    #pragma unroll
    for (int off = 32; off; off >>= 1) s += __shfl_xor(s, off);
    if (lane == 0) red[w] = s;
    __syncthreads();
    s = red[0] + red[1] + red[2] + red[3];
    float inv = 1.f / s;
    #pragma unroll
    for (int k = 0; k < 4; ++k) {
        int j = tid + 256 * k;
        if (j < Ccls) out[(size_t)b * Ccls + j] = e[k] * inv;
    }
}

// =============================================================== orchestration
extern "C" void kernel_launch(void* const* d_in, const int* in_sizes, int n_in,
                              void* d_out, int out_size, void* d_ws, size_t ws_size,
                              hipStream_t stream) {
    const float* image   = (const float*)d_in[0];
    const int*   question= (const int*)  d_in[1];
    const float* embed   = (const float*)d_in[2];
    const float* W_img   = (const float*)d_in[3];
    const float* b_img   = (const float*)d_in[4];
    const float* W_uni   = (const float*)d_in[5];
    const float* b_uni   = (const float*)d_in[6];
    const float* W_bi    = (const float*)d_in[7];
    const float* b_bi    = (const float*)d_in[8];
    const float* W_tri   = (const float*)d_in[9];
    const float* b_tri   = (const float*)d_in[10];
    const float* lstm_k  = (const float*)d_in[11];
    const float* lstm_rk = (const float*)d_in[12];
    const float* lstm_b  = (const float*)d_in[13];
    const float* W_corr  = (const float*)d_in[14];
    const float* b_corr  = (const float*)d_in[15];
    const float* W_qe    = (const float*)d_in[16];
    const float* b_qe    = (const float*)d_in[17];
    const float* W_ie    = (const float*)d_in[18];
    const float* b_ie    = (const float*)d_in[19];
    const float* w_qa    = (const float*)d_in[20];
    const float* w_ia    = (const float*)d_in[22];
    const float* W_w     = (const float*)d_in[24];
    const float* b_w     = (const float*)d_in[25];
    const float* W_p     = (const float*)d_in[26];
    const float* b_p     = (const float*)d_in[27];
    const float* W_s     = (const float*)d_in[28];
    const float* b_s     = (const float*)d_in[29];
    const float* W_fc1   = (const float*)d_in[30];
    const float* b_fc1   = (const float*)d_in[31];
    const float* W_fc    = (const float*)d_in[32];
    const float* b_fc    = (const float*)d_in[33];

    float* p = (float*)d_ws;
    size_t off = 0;
    auto take = [&](size_t n) { float* r = p + off; off += n; return r; };
    auto take_s = [&](size_t n) { short* r = (short*)(p + off); off += n / 2; return r; };
    float* bufB   = take((size_t)Bq * Nimg * Hd);   // image2 -> Y -> Qc2 -> img_embed
    float* xp     = take((size_t)Bq * Tseq * H4);   // xp, then qe0-2 + s_part tail
    float* wm0    = take((size_t)Bq * Tseq * Nimg); // later: catb/fc1b/logits
    float* wm1    = take((size_t)Bq * Tseq * Nimg); // later: s0-2/hw/hp/hsv
    float* wm2    = take((size_t)Bq * Tseq * Nimg);
    float* hbuf   = take((size_t)Bq * Hd);
    float* cbuf   = take((size_t)Bq * Hd);
    float* zgp    = take((size_t)2 * Bq * H4);
    float* qlogp  = take((size_t)3 * Bq * 4 * Tseq);
    float* qatt0  = take((size_t)Bq * Tseq);
    float* qatt1  = take((size_t)Bq * Tseq);
    float* qatt2  = take((size_t)Bq * Tseq);
    float* ilogp  = take((size_t)2 * 3 * Bq * Nimg);
    float* iatt0  = take((size_t)Bq * Nimg);
    float* iatt1  = take((size_t)Bq * Nimg);
    float* iatt2  = take((size_t)Bq * Nimg);
    float* qb     = take((size_t)MT3);
    // split-bf16 buffers
    short* imgS2   = take_s((size_t)Bq * Nimg * 1024);   // img2 (GEMM-2 output)
    short* words2  = take_s((size_t)Bq * Tseq * 1024);
    short* phrase2 = take_s((size_t)Bq * Tseq * 1024);
    short* sentn2  = take_s((size_t)Bq * Tseq * 1024);
    short* WimgT2  = take_s((size_t)Hd * KP);
    short* WieT2   = take_s((size_t)Hd * KP);
    short* WcorrR2 = take_s((size_t)Hd * KP);            // adjacent pair: [WcorrR2 | WqeT2]
    short* WqeT2   = take_s((size_t)Hd * KP);            // = WcorrR2 + 512*KP (1024-row B)
    short* WconvT2 = take_s((size_t)6 * Hd * KP);        // 3072 rows
    short* lkT2    = take_s((size_t)H4 * KP);            // 2048 rows

    float* qe0 = xp;                                // xp dead after LSTM
    float* qe1 = xp + (size_t)Bq * Tseq * Hd;
    float* qe2 = xp + 2 * (size_t)Bq * Tseq * Hd;
    float* s_part = xp + 3 * (size_t)Bq * Tseq * Hd;          // 12*Bq*Hd fits tail
    float* Y      = bufB;                                      // conv tap outputs
    short* image2 = (short*)bufB;                              // input split (dead before Y)
    short* Qc2    = (short*)bufB;                              // Q@W_corr^T split (dead before img_embed)
    float* catb   = wm0;                                       // wm0 dead after step 11
    float* fc1b   = wm0 + (size_t)Bq * 2 * Hd;
    float* logits = wm0 + 2 * (size_t)Bq * 2 * Hd;
    float* s0     = wm1;                                       // wm1 dead after step 11
    float* s1     = wm1 + 1 * (size_t)Bq * Hd;
    float* s2     = wm1 + 2 * (size_t)Bq * Hd;
    float* hw     = wm1 + 3 * (size_t)Bq * Hd;
    float* hp     = wm1 + 4 * (size_t)Bq * Hd;
    float* hsv    = wm1 + 5 * (size_t)Bq * Hd;

    const int MI = Bq * Nimg;   // 50176
    const int MT = Bq * Tseq;   // 6656

    // 0. ALL weight splits in one launch (z==1: W_corr rows for Qc)
    wsplit_all_kernel<<<dim3(8, 8, 14), 256, 0, stream>>>(
        W_img, W_corr, W_ie, W_qe, W_uni, W_bi, W_tri, lstm_k,
        WimgT2, WcorrR2, WieT2, WqeT2, WconvT2, lkT2);

    // 1. word embeddings (split only)
    embed_kernel<<<MT, 128, 0, stream>>>(question, embed, words2);
    // 2. split image into bufB bytes, then img2 = split(tanh(image @ W_img + b))
    split_kernel<<<MI / 2, 256, 0, stream>>>(image, image2);
    mfma_gemm8_kernel<1, 1><<<dim3((MI / 256) * (Hd / 256)), 512, 0, stream>>>(
        image2, WimgT2, b_img, nullptr, imgS2, MI, Hd);
    // 3. conv taps as one GEMM into bufB (image2 dead now) + shifted combine
    mfma_gemm8_kernel<0, 0><<<dim3((MT / 256) * (3072 / 256)), 512, 0, stream>>>(
        words2, WconvT2, nullptr, Y, nullptr, MT, 3072);
    conv_combine_kernel<<<(MT * Hd) / 256, 256, 0, stream>>>(Y, b_uni, b_bi, b_tri, phrase2);
    // 4. xp = phrase @ lstm_k + lstm_b
    mfma_gemm8_kernel<0, 0><<<dim3((MT / 256) * (H4 / 256)), 512, 0, stream>>>(
        phrase2, lkT2, lstm_b, xp, nullptr, MT, H4);
    // 5. LSTM (fp32 split-K GEMM + fused combine/gates; sentn written split)
    hipMemsetAsync(hbuf, 0, (size_t)Bq * Hd * sizeof(float), stream);
    hipMemsetAsync(cbuf, 0, (size_t)Bq * Hd * sizeof(float), stream);
    for (int t = 0; t < Tseq; ++t) {
        lstm_gemm_kernel<<<dim3(32, 4, 2), 256, 0, stream>>>(hbuf, lstm_rk, zgp);
        lstm_gates_kernel<<<(Bq * Hd) / 256, 256, 0, stream>>>(zgp, xp, cbuf, hbuf, sentn2, t);
    }
    // 6. qb = Q . b_corr; MERGED GEMM: [Qc | qe] = Q @ [W_corr^T | W_qe] (N=1024, OUT=2)
    //    cols 0-511 -> Qc2 split-bf16 (bufB bytes, no bias); cols 512-1023 -> qe fp32 + b_qe
    qb_kernel<<<MT3 / 4, 256, 0, stream>>>(words2, b_corr, qb);
    mfma_gemm8_kernel<0, 2><<<dim3((MT3 / 256) * (1024 / 256)), 512, 0, stream>>>(
        words2, WcorrR2, b_qe, qe0, Qc2, MT3, 1024);
    // 7. fused affinity maps: wm = tanh(Qc . img^T + qb)
    wm3_mfma_kernel<<<dim3(2, Bq), 256, 0, stream>>>(Qc2, imgS2, qb, wm0, wm1, wm2);
    // 8. img_embed -> fp32 bufB (overwrites Qc2; wm3 done)
    mfma_gemm8_kernel<0, 0><<<dim3((MI / 256) * (Hd / 256)), 512, 0, stream>>>(
        imgS2, WieT2, b_ie, bufB, nullptr, MI, Hd);
    // 10. fused qlog (all 3 calls) + merged question softmaxes
    qlog3_kernel<<<dim3(Bq, 2), 256, 0, stream>>>(wm0, wm1, wm2, bufB, qe0, qe1, qe2, w_qa, qlogp);
    softmaxT_part_kernel<<<dim3(Bq, 3), 64, 0, stream>>>(qlogp, qatt0);
    // 11. merged ilog (3 levels, h-split, t-outer 2-pass regs) + merged image softmaxes
    ilog3_kernel<<<dim3(Bq, 4, 3), 256, 0, stream>>>(wm0, qe0, bufB, w_ia, ilogp);
    softmax_N_kernel<<<dim3(Bq, 3), 64, 0, stream>>>(ilogp, iatt0);
    // 12. fused feature pooling (wm0/wm1 now reusable)
    feat3_kernel<<<dim3(Bq, 4), 256, 0, stream>>>(qatt0, qatt1, qatt2, iatt0, iatt1, iatt2,
                                                  words2, phrase2, sentn2, imgS2, s_part);
    feat_combine_kernel<<<(3 * Bq * Hd) / 256, 256, 0, stream>>>(s_part, s0, s1, s2);
    // 13. head (fp32)
    gemm_kernel<1><<<dim3(Hd / 64, Bq / 64), 256, 0, stream>>>(
        s0, Hd, W_w, Hd, b_w, hw, Hd, Bq, Hd, Hd);
    concat_kernel<<<(Bq * Hd) / 256, 256, 0, stream>>>(s1, hw, catb);
    gemm_kernel<1><<<dim3(Hd / 64, Bq / 64), 256, 0, stream>>>(
        catb, 2 * Hd, W_p, Hd, b_p, hp, Hd, Bq, Hd, 2 * Hd);
    concat_kernel<<<(Bq * Hd) / 256, 256, 0, stream>>>(s2, hp, catb);
    gemm_kernel<1><<<dim3(Hd / 64, Bq / 64), 256, 0, stream>>>(
        catb, 2 * Hd, W_s, Hd, b_s, hsv, Hd, Bq, Hd, 2 * Hd);
    gemm_kernel<2><<<dim3((2 * Hd) / 64, Bq / 64), 256, 0, stream>>>(
        hsv, Hd, W_fc1, 2 * Hd, b_fc1, fc1b, 2 * Hd, Bq, 2 * Hd, Hd);
    gemm_kernel<0><<<dim3((Ccls + 63) / 64, Bq / 64), 256, 0, stream>>>(
        fc1b, 2 * Hd, W_fc, Ccls, b_fc, logits, Ccls, Bq, Ccls, 2 * Hd);
    softmax_C_kernel<<<Bq, 256, 0, stream>>>(logits, (float*)d_out);
}

// Round 27
// 1763.088 us; speedup vs baseline: 1.0147x; 1.0147x over previous
//
#include <hip/hip_runtime.h>
#include <hip/hip_bf16.h>
#include <math.h>

#define Bq   256
#define Nimg 196
#define Tseq 26
#define Hd   512
#define H4   2048
#define Ccls 1000
#define KP   1536   // 3*Hd split-K'
#define MT3  19968  // 3 * Bq * Tseq

typedef int   int4v  __attribute__((ext_vector_type(4)));
typedef float f32x4  __attribute__((ext_vector_type(4)));

#define SWZ8(x) ((x) ^ (((x) >> 3) & 7))   // LDS slot swizzle (involution, bits0-2 ^= bits3-5)

// ------------------------------------------------------------ fast activations
__device__ __forceinline__ float fast_tanh(float x) {
    float e = __expf(2.0f * x);
    return 1.0f - 2.0f * __builtin_amdgcn_rcpf(e + 1.0f);
}
__device__ __forceinline__ float fast_sigmoid(float x) {
    return __builtin_amdgcn_rcpf(1.0f + __expf(-x));
}

// ------------------------------------------------------------- bf16 split utils
__device__ __forceinline__ short f2bf(float x) {
    union { float f; unsigned u; } a; a.f = x;
    unsigned r = a.u + 0x7FFF + ((a.u >> 16) & 1);   // RNE
    return (short)(r >> 16);
}
__device__ __forceinline__ float bf2f(short b) {
    union { float f; unsigned u; } a; a.u = ((unsigned)(unsigned short)b) << 16;
    return a.f;
}

// ---------------------------------------------------------------- embed gather
__global__ void embed_kernel(const int* __restrict__ q, const float* __restrict__ table,
                             short* __restrict__ words2) {
    int row = blockIdx.x;               // b*T + t
    int tok = q[row];
    int c4 = threadIdx.x * 4;           // block 128
    float4 v = *reinterpret_cast<const float4*>(table + (size_t)tok * Hd + c4);
    short h0 = f2bf(v.x), h1 = f2bf(v.y), h2 = f2bf(v.z), h3 = f2bf(v.w);
    short l0 = f2bf(v.x - bf2f(h0)), l1 = f2bf(v.y - bf2f(h1));
    short l2 = f2bf(v.z - bf2f(h2)), l3 = f2bf(v.w - bf2f(h3));
    *reinterpret_cast<short4*>(words2 + (size_t)row * 1024 + c4) = make_short4(h0, h1, h2, h3);
    *reinterpret_cast<short4*>(words2 + (size_t)row * 1024 + 512 + c4) = make_short4(l0, l1, l2, l3);
}

// ---- X [M,512] fp32 -> X2 [M,1024] bf16 (hi|lo). grid M/2 x 256
__global__ void split_kernel(const float* __restrict__ X, short* __restrict__ X2) {
    int i4 = blockIdx.x * 256 + threadIdx.x;       // float4 index over M*128
    int m = i4 >> 7, c4 = (i4 & 127) * 4;
    float4 v = *reinterpret_cast<const float4*>(X + ((size_t)m << 9) + c4);
    short h0 = f2bf(v.x), h1 = f2bf(v.y), h2 = f2bf(v.z), h3 = f2bf(v.w);
    short l0 = f2bf(v.x - bf2f(h0)), l1 = f2bf(v.y - bf2f(h1));
    short l2 = f2bf(v.z - bf2f(h2)), l3 = f2bf(v.w - bf2f(h3));
    *reinterpret_cast<short4*>(X2 + (size_t)m * 1024 + c4) = make_short4(h0, h1, h2, h3);
    *reinterpret_cast<short4*>(X2 + (size_t)m * 1024 + 512 + c4) = make_short4(l0, l1, l2, l3);
}

// ---- ALL weight splits in one launch. grid (8, 8, 14), block 256.
// z==1: W_corr ROWS (for Qc = Q @ W_corr^T); all other z: columns (transposed).
__global__ __launch_bounds__(256) void wsplit_all_kernel(
    const float* __restrict__ W_img, const float* __restrict__ W_corr,
    const float* __restrict__ W_ie, const float* __restrict__ W_qe,
    const float* __restrict__ W_uni, const float* __restrict__ W_bi,
    const float* __restrict__ W_tri, const float* __restrict__ lstm_k,
    short* __restrict__ WimgT2, short* __restrict__ WcorrR2,
    short* __restrict__ WieT2, short* __restrict__ WqeT2,
    short* __restrict__ WconvT2, short* __restrict__ lkT2) {
    const int z = blockIdx.z;
    const int tid = threadIdx.x;
    const int k0 = blockIdx.y * 64;
    const size_t HK = (size_t)Hd * KP;
    if (z == 1) {   // rows of W_corr, no transpose
        const int n0 = blockIdx.x * 64;
        const int n = tid >> 2, ksub = (tid & 3) * 16;
        const float* src = W_corr + (size_t)(n0 + n) * Hd + k0 + ksub;
        size_t base = (size_t)(n0 + n) * KP + k0 + ksub;
        #pragma unroll
        for (int k = 0; k < 16; ++k) {
            float x = src[k];
            short h = f2bf(x);
            short l = f2bf(x - bf2f(h));
            WcorrR2[base + k] = h;
            WcorrR2[base + 512 + k] = h;
            WcorrR2[base + 1024 + k] = l;
        }
        return;
    }
    const float* W; short* WT2; int Nw, n0;
    if (z < 10) {
        Nw = Hd; n0 = blockIdx.x * 64;
        switch (z) {
            case 0: W = W_img;  WT2 = WimgT2;  break;
            case 2: W = W_ie;   WT2 = WieT2;   break;
            case 3: W = W_qe;   WT2 = WqeT2;   break;
            case 4: W = W_uni;                     WT2 = WconvT2 + 0 * HK; break;
            case 5: W = W_bi;                      WT2 = WconvT2 + 1 * HK; break;
            case 6: W = W_bi + (size_t)Hd * Hd;    WT2 = WconvT2 + 2 * HK; break;
            case 7: W = W_tri;                     WT2 = WconvT2 + 3 * HK; break;
            case 8: W = W_tri + (size_t)Hd * Hd;   WT2 = WconvT2 + 4 * HK; break;
            default:W = W_tri + 2 * (size_t)Hd * Hd; WT2 = WconvT2 + 5 * HK; break;
        }
    } else {
        Nw = H4; W = lstm_k; WT2 = lkT2;
        n0 = ((z - 10) * 8 + blockIdx.x) * 64;
    }
    __shared__ float tile[64][65];
    #pragma unroll
    for (int p = 0; p < 16; ++p) {
        int r = p * 4 + (tid >> 6);
        int c = tid & 63;
        tile[r][c] = W[(size_t)(k0 + r) * Nw + n0 + c];
    }
    __syncthreads();
    const int n = tid >> 2;
    const int ksub = (tid & 3) * 16;
    size_t base = (size_t)(n0 + n) * KP + k0 + ksub;
    #pragma unroll
    for (int k = 0; k < 16; ++k) {
        float x = tile[ksub + k][n];
        short h = f2bf(x);
        short l = f2bf(x - bf2f(h));
        WT2[base + k] = h;
        WT2[base + 512 + k] = h;
        WT2[base + 1024 + k] = l;
    }
}

// ---- qb[r] = Q[r,:] . b_corr  (split-bf16 Q rows). grid MT3/4, block 256
__global__ __launch_bounds__(256) void qb_kernel(const short* __restrict__ Q2,
                                                 const float* __restrict__ b_corr,
                                                 float* __restrict__ qb) {
    const int tid = threadIdx.x, lane = tid & 63, wid = tid >> 6;
    const int r = blockIdx.x * 4 + wid;
    const short* row = Q2 + (size_t)r * 1024 + lane * 8;
    float v = 0.f;
    #pragma unroll
    for (int k = 0; k < 8; ++k) {
        float x = bf2f(row[k]) + bf2f(row[512 + k]);
        v += x * b_corr[lane * 8 + k];
    }
    #pragma unroll
    for (int off = 32; off; off >>= 1) v += __shfl_xor(v, off);
    if (lane == 0) qb[r] = v;
}

// -------------------------------------------------- split-bf16 MFMA GEMM
__device__ __forceinline__ void mfma16(f32x4& acc, int4v a, int4v b) {
    asm volatile("v_mfma_f32_16x16x32_bf16 %0, %1, %2, %0" : "+v"(acc) : "v"(a), "v"(b));
}

// ===================== 8-phase 256x256 tile, BK=64, 8 waves, counted vmcnt =====================
// R21 schedule (spread STAGE across phases, vmcnt(2)) + 1D grid with bijective XCD chunking.
// OUT: 0 fp32 C; 1 split-bf16 C2; 2 MIXED (col<512 -> split C2 no bias, col>=512 -> fp32 C+bias).
// Requires M%256==0, N%256==0. Accumulation order identical across variants (32-k chunks asc).
template <int ACT, int OUT>
__global__ __launch_bounds__(512) void mfma_gemm8_kernel(
    const short* __restrict__ A2, const short* __restrict__ W2T,
    const float* __restrict__ bias, float* __restrict__ C, short* __restrict__ C2,
    int M, int N) {
    __shared__ __align__(16) short L[2][2][4][4096];  // [slot][A/B][h*2+kh][512 slots * 8]
    const int tid = threadIdx.x;
    const int lane = tid & 63, wid = tid >> 6;
    // bijective chunked XCD swizzle (m204): XCD k gets a contiguous chunk of logical IDs
    const int Cn = N >> 8;
    const int nwg = (M >> 8) * Cn;
    int Lb = blockIdx.x;
    int xcd = Lb & 7, lq = Lb >> 3;
    int q8 = nwg >> 3, r8 = nwg & 7;
    int logical = (xcd < r8 ? xcd * (q8 + 1) : r8 * (q8 + 1) + (xcd - r8) * q8) + lq;
    const int row0 = (logical / Cn) << 8, col0 = (logical % Cn) << 8;
    const int wm = wid >> 2, wn = wid & 3;    // 2M x 4N waves; per-wave out 128x64
    // staging decode (identical scheme to proven 2-phase kernel, 512 slots/sub-block)
    const int sdec = SWZ8(tid);
    const int frs = sdec >> 6, rs = (sdec >> 2) & 15, kb = sdec & 3;
    const int koff = kb * 8;
    const int aro = frs * 16 + rs;            // 0..127 row within half
    const short* aptr[2]; const short* bptr[2];
    aptr[0] = A2 + (size_t)(row0 + aro) * 1024;
    aptr[1] = A2 + (size_t)(row0 + 128 + aro) * 1024;
    bptr[0] = W2T + (size_t)(col0 + aro) * KP;
    bptr[1] = W2T + (size_t)(col0 + 128 + aro) * KP;
    const int ldso = wid * 64 * 8;            // wave-uniform dest base within sub-block
    auto STAGE = [&](int slot, int tile, int p) {
        int h = p & 1, kh = p >> 1;
        int kk = tile * 64 + kh * 32 + koff;
        int ka = kk >= 1024 ? kk - 1024 : kk;   // A wrap: hi|lo|hi
        __builtin_amdgcn_global_load_lds(
            (const __attribute__((address_space(1))) void*)(aptr[h] + ka),
            (__attribute__((address_space(3))) void*)(&L[slot][0][h * 2 + kh][ldso]),
            16, 0, 0);
        __builtin_amdgcn_global_load_lds(
            (const __attribute__((address_space(1))) void*)(bptr[h] + kk),
            (__attribute__((address_space(3))) void*)(&L[slot][1][h * 2 + kh][ldso]),
            16, 0, 0);
    };
    f32x4 acc[8][4] = {};
    #pragma unroll
    for (int p = 0; p < 4; ++p) STAGE(0, 0, p);   // prologue: tile 0 (8 loads)
    const int NT = KP / 64;   // 24
    for (int t = 0; t < NT; ++t) {
        const int sl = t & 1;
        int4v bfr[4][2];
        #pragma unroll
        for (int p = 0; p < 4; ++p) {
            if (p == 0) {
                if (t + 1 < NT) {
                    STAGE(sl ^ 1, t + 1, 0);
                    asm volatile("s_waitcnt vmcnt(2)" ::: "memory");  // tile t's 8 landed (mine)
                } else {
                    asm volatile("s_waitcnt vmcnt(0)" ::: "memory");
                }
                __builtin_amdgcn_s_barrier();       // everyone's tile-t loads landed
                __builtin_amdgcn_sched_barrier(0);
                #pragma unroll
                for (int nf = 0; nf < 4; ++nf)
                    #pragma unroll
                    for (int kh = 0; kh < 2; ++kh) {
                        int off = ((wn & 1) * 4 + nf) * 64 + (lane & 15) * 4 + (lane >> 4);
                        bfr[nf][kh] = *reinterpret_cast<const int4v*>(
                            &L[sl][1][(wn >> 1) * 2 + kh][SWZ8(off) * 8]);
                    }
            } else {
                if (t + 1 < NT) STAGE(sl ^ 1, t + 1, p);
            }
            int4v af[2][2];
            #pragma unroll
            for (int i = 0; i < 2; ++i)
                #pragma unroll
                for (int kh = 0; kh < 2; ++kh) {
                    int off = (p * 2 + i) * 64 + (lane & 15) * 4 + (lane >> 4);
                    af[i][kh] = *reinterpret_cast<const int4v*>(
                        &L[sl][0][wm * 2 + kh][SWZ8(off) * 8]);
                }
            __builtin_amdgcn_s_setprio(1);
            #pragma unroll
            for (int i = 0; i < 2; ++i)
                #pragma unroll
                for (int nf = 0; nf < 4; ++nf)
                    #pragma unroll
                    for (int kh = 0; kh < 2; ++kh)
                        mfma16(acc[p * 2 + i][nf], af[i][kh], bfr[nf][kh]);
            __builtin_amdgcn_s_setprio(0);
        }
        asm volatile("s_waitcnt lgkmcnt(0)" ::: "memory");  // my reads of slot sl done
        __builtin_amdgcn_s_barrier();                        // all waves done reading sl
        __builtin_amdgcn_sched_barrier(0);                   // next iter's STAGE may not cross
    }
    asm volatile("s_nop 7\n\ts_nop 7" ::: "memory");   // MFMA->VALU read hazard
    #pragma unroll
    for (int mf = 0; mf < 8; ++mf) {
        #pragma unroll
        for (int nf = 0; nf < 4; ++nf) {
            int col = col0 + wn * 64 + nf * 16 + (lane & 15);
            float bv;
            if (OUT == 2) bv = (col >= 512) ? bias[col - 512] : 0.f;
            else bv = bias ? bias[col] : 0.f;
            #pragma unroll
            for (int r = 0; r < 4; ++r) {
                int row = row0 + wm * 128 + mf * 16 + (lane >> 4) * 4 + r;
                float v = acc[mf][nf][r] + bv;
                if (ACT == 1) v = fast_tanh(v);
                if (OUT == 0) {
                    C[(size_t)row * N + col] = v;
                } else if (OUT == 1) {
                    short h = f2bf(v), l = f2bf(v - bf2f(h));
                    C2[(size_t)row * 1024 + col] = h;
                    C2[(size_t)row * 1024 + 512 + col] = l;
                } else {   // OUT == 2: mixed Qc|qe
                    if (col < 512) {
                        short h = f2bf(v), l = f2bf(v - bf2f(h));
                        C2[(size_t)row * 1024 + col] = h;
                        C2[(size_t)row * 1024 + 512 + col] = l;
                    } else {
                        C[(size_t)row * Hd + (col - 512)] = v;
                    }
                }
            }
        }
    }
}

// ===================== DUAL-segment batched GEMM (same body, runtime params) =====================
// seg0: blocks [0,nwg0): Qc|qe merged (OUT=2); seg1: blocks [nwg0,..): ie (OUT=0, +bias).
// Round-count lever: ceil((nwg0+nwg1)/256) < ceil(nwg0/256)+ceil(nwg1/256).
__global__ __launch_bounds__(512) void mfma_gemm8_dual_kernel(
    const short* __restrict__ A0, const short* __restrict__ W0,
    const float* __restrict__ bias0, float* __restrict__ C0, short* __restrict__ C20,
    int M0, int N0, int nwg0,
    const short* __restrict__ A1, const short* __restrict__ W1,
    const float* __restrict__ bias1, float* __restrict__ C1,
    int M1, int N1) {
    __shared__ __align__(16) short L[2][2][4][4096];
    const int tid = threadIdx.x;
    const int lane = tid & 63, wid = tid >> 6;
    // segment select (per-block uniform)
    const short* A2; const short* W2T; const float* bias; float* C; short* C2;
    int N, OUT, nwg, Lb;
    if ((int)blockIdx.x < nwg0) {
        A2 = A0; W2T = W0; bias = bias0; C = C0; C2 = C20;
        N = N0; OUT = 2; nwg = nwg0; Lb = blockIdx.x;
    } else {
        A2 = A1; W2T = W1; bias = bias1; C = C1; C2 = nullptr;
        N = N1; OUT = 0; nwg = (M1 >> 8) * (N1 >> 8); Lb = blockIdx.x - nwg0;
    }
    const int Cn = N >> 8;
    int xcd = Lb & 7, lq = Lb >> 3;
    int q8 = nwg >> 3, r8 = nwg & 7;
    int logical = (xcd < r8 ? xcd * (q8 + 1) : r8 * (q8 + 1) + (xcd - r8) * q8) + lq;
    const int row0 = (logical / Cn) << 8, col0 = (logical % Cn) << 8;
    const int wm = wid >> 2, wn = wid & 3;
    const int sdec = SWZ8(tid);
    const int frs = sdec >> 6, rs = (sdec >> 2) & 15, kb = sdec & 3;
    const int koff = kb * 8;
    const int aro = frs * 16 + rs;
    const short* aptr[2]; const short* bptr[2];
    aptr[0] = A2 + (size_t)(row0 + aro) * 1024;
    aptr[1] = A2 + (size_t)(row0 + 128 + aro) * 1024;
    bptr[0] = W2T + (size_t)(col0 + aro) * KP;
    bptr[1] = W2T + (size_t)(col0 + 128 + aro) * KP;
    const int ldso = wid * 64 * 8;
    auto STAGE = [&](int slot, int tile, int p) {
        int h = p & 1, kh = p >> 1;
        int kk = tile * 64 + kh * 32 + koff;
        int ka = kk >= 1024 ? kk - 1024 : kk;   // A wrap: hi|lo|hi
        __builtin_amdgcn_global_load_lds(
            (const __attribute__((address_space(1))) void*)(aptr[h] + ka),
            (__attribute__((address_space(3))) void*)(&L[slot][0][h * 2 + kh][ldso]),
            16, 0, 0);
        __builtin_amdgcn_global_load_lds(
            (const __attribute__((address_space(1))) void*)(bptr[h] + kk),
            (__attribute__((address_space(3))) void*)(&L[slot][1][h * 2 + kh][ldso]),
            16, 0, 0);
    };
    f32x4 acc[8][4] = {};
    #pragma unroll
    for (int p = 0; p < 4; ++p) STAGE(0, 0, p);
    const int NT = KP / 64;   // 24
    for (int t = 0; t < NT; ++t) {
        const int sl = t & 1;
        int4v bfr[4][2];
        #pragma unroll
        for (int p = 0; p < 4; ++p) {
            if (p == 0) {
                if (t + 1 < NT) {
                    STAGE(sl ^ 1, t + 1, 0);
                    asm volatile("s_waitcnt vmcnt(2)" ::: "memory");
                } else {
                    asm volatile("s_waitcnt vmcnt(0)" ::: "memory");
                }
                __builtin_amdgcn_s_barrier();
                __builtin_amdgcn_sched_barrier(0);
                #pragma unroll
                for (int nf = 0; nf < 4; ++nf)
                    #pragma unroll
                    for (int kh = 0; kh < 2; ++kh) {
                        int off = ((wn & 1) * 4 + nf) * 64 + (lane & 15) * 4 + (lane >> 4);
                        bfr[nf][kh] = *reinterpret_cast<const int4v*>(
                            &L[sl][1][(wn >> 1) * 2 + kh][SWZ8(off) * 8]);
                    }
            } else {
                if (t + 1 < NT) STAGE(sl ^ 1, t + 1, p);
            }
            int4v af[2][2];
            #pragma unroll
            for (int i = 0; i < 2; ++i)
                #pragma unroll
                for (int kh = 0; kh < 2; ++kh) {
                    int off = (p * 2 + i) * 64 + (lane & 15) * 4 + (lane >> 4);
                    af[i][kh] = *reinterpret_cast<const int4v*>(
                        &L[sl][0][wm * 2 + kh][SWZ8(off) * 8]);
                }
            __builtin_amdgcn_s_setprio(1);
            #pragma unroll
            for (int i = 0; i < 2; ++i)
                #pragma unroll
                for (int nf = 0; nf < 4; ++nf)
                    #pragma unroll
                    for (int kh = 0; kh < 2; ++kh)
                        mfma16(acc[p * 2 + i][nf], af[i][kh], bfr[nf][kh]);
            __builtin_amdgcn_s_setprio(0);
        }
        asm volatile("s_waitcnt lgkmcnt(0)" ::: "memory");
        __builtin_amdgcn_s_barrier();
        __builtin_amdgcn_sched_barrier(0);
    }
    asm volatile("s_nop 7\n\ts_nop 7" ::: "memory");
    #pragma unroll
    for (int mf = 0; mf < 8; ++mf) {
        #pragma unroll
        for (int nf = 0; nf < 4; ++nf) {
            int col = col0 + wn * 64 + nf * 16 + (lane & 15);
            float bv;
            if (OUT == 2) bv = (col >= 512) ? bias[col - 512] : 0.f;
            else bv = bias[col];
            #pragma unroll
            for (int r = 0; r < 4; ++r) {
                int row = row0 + wm * 128 + mf * 16 + (lane >> 4) * 4 + r;
                float v = acc[mf][nf][r] + bv;
                if (OUT == 0) {
                    C[(size_t)row * N + col] = v;
                } else {   // OUT == 2: mixed Qc|qe
                    if (col < 512) {
                        short h = f2bf(v), l = f2bf(v - bf2f(h));
                        C2[(size_t)row * 1024 + col] = h;
                        C2[(size_t)row * 1024 + 512 + col] = l;
                    } else {
                        C[(size_t)row * Hd + (col - 512)] = v;
                    }
                }
            }
        }
    }
}

// ----------------- batched MFMA: wm[lvl,b] = tanh(Qc[lvl,b] (26x512) @ img[b]^T + qb)
__global__ __launch_bounds__(256) void wm3_mfma_kernel(
    const short* __restrict__ Qc2, const short* __restrict__ img2,
    const float* __restrict__ qb, float* __restrict__ wm0, float* __restrict__ wm1,
    float* __restrict__ wm2) {
    __shared__ __align__(16) short Asl[2][4096];
    __shared__ __align__(16) short Bsl[2][4096];
    const int tid = threadIdx.x;
    const int lane = tid & 63, wid = tid >> 6;
    const int col0 = blockIdx.x * 128;       // n-tile
    const int b = blockIdx.y;
    const int wmq = wid >> 1, wn = wid & 1;
    const short* ab[2]; const short* bb[2]; int koff[2];
    #pragma unroll
    for (int c = 0; c < 2; ++c) {
        int d = c * 256 + tid;
        int s = SWZ8(d);
        int fr = s >> 6, r = (s >> 2) & 15, kb = s & 3;
        koff[c] = kb * 8;
        int arow = fr * 16 + r;
        int lvl = arow / 26, at = arow - lvl * 26;
        if (arow >= 78) { lvl = 0; at = 0; }
        ab[c] = Qc2 + ((size_t)lvl * (Bq * Tseq) + (size_t)(b * 26 + at)) * 1024;
        int brow = col0 + fr * 16 + r;
        if (brow > 195) brow = 195;
        bb[c] = img2 + ((size_t)(b * 196 + brow)) * 1024;
    }
    auto STAGE = [&](int buf, int k0) {
        #pragma unroll
        for (int c = 0; c < 2; ++c) {
            int kk = k0 + koff[c];
            int ka = kk >= 1024 ? kk - 1024 : kk;      // A: hi|lo|hi
            int kbv = kk >= 512 ? kk - 512 : kk;       // B: hi|hi|lo
            __builtin_amdgcn_global_load_lds(
                (const __attribute__((address_space(1))) void*)(ab[c] + ka),
                (__attribute__((address_space(3))) void*)(&Asl[buf][(c * 256 + wid * 64) * 8]),
                16, 0, 0);
            __builtin_amdgcn_global_load_lds(
                (const __attribute__((address_space(1))) void*)(bb[c] + kbv),
                (__attribute__((address_space(3))) void*)(&Bsl[buf][(c * 256 + wid * 64) * 8]),
                16, 0, 0);
        }
    };
    f32x4 acc[4][4] = {};
    STAGE(0, 0);
    int cur = 0;
    for (int k0 = 0; k0 < KP; k0 += 32) {
        if (k0 + 32 < KP) {
            STAGE(cur ^ 1, k0 + 32);
            asm volatile("s_waitcnt vmcnt(4)" ::: "memory");
        } else {
            asm volatile("s_waitcnt vmcnt(0)" ::: "memory");
        }
        __builtin_amdgcn_s_barrier();
        __builtin_amdgcn_sched_barrier(0);
        int4v af[4], bfr[4];
        #pragma unroll
        for (int f = 0; f < 4; ++f) {
            int sa = (wmq * 4 + f) * 64 + (lane & 15) * 4 + (lane >> 4);
            af[f] = *reinterpret_cast<const int4v*>(&Asl[cur][SWZ8(sa) * 8]);
            int sb = (wn * 4 + f) * 64 + (lane & 15) * 4 + (lane >> 4);
            bfr[f] = *reinterpret_cast<const int4v*>(&Bsl[cur][SWZ8(sb) * 8]);
        }
        #pragma unroll
        for (int i = 0; i < 4; ++i)
            #pragma unroll
            for (int j = 0; j < 4; ++j)
                mfma16(acc[i][j], af[i], bfr[j]);
        asm volatile("s_waitcnt lgkmcnt(0)" ::: "memory");
        __builtin_amdgcn_s_barrier();
        __builtin_amdgcn_sched_barrier(0);
        cur ^= 1;
    }
    asm volatile("s_nop 7\n\ts_nop 7" ::: "memory");
    #pragma unroll
    for (int i = 0; i < 4; ++i) {
        #pragma unroll
        for (int j = 0; j < 4; ++j) {
            int col = col0 + wn * 64 + j * 16 + (lane & 15);
            if (col >= Nimg) continue;
            #pragma unroll
            for (int r = 0; r < 4; ++r) {
                int row = wmq * 64 + i * 16 + (lane >> 4) * 4 + r;
                if (row >= 78) continue;
                int lvl = row / 26, t = row - lvl * 26;
                float* dst = (lvl == 0) ? wm0 : (lvl == 1) ? wm1 : wm2;
                float qbv = qb[(size_t)lvl * (Bq * Tseq) + b * 26 + t];
                dst[((size_t)(b * 26 + t)) * Nimg + col] = fast_tanh(acc[i][j][r] + qbv);
            }
        }
    }
}

// ---- conv tap-combine
__global__ void conv_combine_kernel(const float* __restrict__ Y,
                                    const float* __restrict__ bu, const float* __restrict__ bb,
                                    const float* __restrict__ bt,
                                    short* __restrict__ phrase2) {
    int idx = blockIdx.x * 256 + threadIdx.x;      // over MT*512
    int m = idx >> 9, c = idx & 511;
    int t = m % Tseq;
    const float* Ym = Y + (size_t)m * 3072;
    float u = Ym[c] + bu[c];
    float bv = bb[c];
    if (t > 0)  bv += Ym[-3072 + 512 + c];
    if (t < 25) bv += Ym[3072 + 1024 + c];
    float tv = Ym[2048 + c] + bt[c];
    if (t > 1)  tv += Ym[-6144 + 1536 + c];
    if (t < 24) tv += Ym[6144 + 2560 + c];
    float ph = fast_tanh(fmaxf(fmaxf(fast_tanh(u), fast_tanh(bv)), fast_tanh(tv)));
    short h = f2bf(ph), l = f2bf(ph - bf2f(h));
    phrase2[(size_t)m * 1024 + c] = h;
    phrase2[(size_t)m * 1024 + 512 + c] = l;
}

// ---------------------------------------------------------------- head GEMM
template <int ACT>  // 0 none, 1 tanh, 2 relu
__global__ __launch_bounds__(256) void gemm_kernel(
    const float* __restrict__ A, int lda,
    const float* __restrict__ W, int ldw,
    const float* __restrict__ bias,
    float* __restrict__ C, int ldc,
    int M, int Ncols, int K) {
    __shared__ float As[16][68];
    __shared__ float Ws[16][68];
    const int tid = threadIdx.x;
    const int tx4 = (tid & 15) * 4, ty4 = (tid >> 4) * 4;
    const int row0 = blockIdx.y * 64, col0 = blockIdx.x * 64;
    const int am = tid >> 2, ak = (tid & 3) * 4;
    const int wk = tid >> 4, wc = (tid & 15) * 4;
    float acc[4][4] = {};
    for (int k0 = 0; k0 < K; k0 += 16) {
        {
            int gr = row0 + am;
            float4 v = make_float4(0.f, 0.f, 0.f, 0.f);
            if (gr < M) v = *reinterpret_cast<const float4*>(A + (size_t)gr * lda + k0 + ak);
            As[ak + 0][am] = v.x; As[ak + 1][am] = v.y; As[ak + 2][am] = v.z; As[ak + 3][am] = v.w;
        }
        {
            int gc = col0 + wc;
            const float* wp = W + (size_t)(k0 + wk) * ldw + gc;
            float4 v = make_float4(0.f, 0.f, 0.f, 0.f);
            if (gc + 3 < Ncols) v = *reinterpret_cast<const float4*>(wp);
            else {
                if (gc + 0 < Ncols) v.x = wp[0];
                if (gc + 1 < Ncols) v.y = wp[1];
                if (gc + 2 < Ncols) v.z = wp[2];
                if (gc + 3 < Ncols) v.w = wp[3];
            }
            Ws[wk][wc + 0] = v.x; Ws[wk][wc + 1] = v.y; Ws[wk][wc + 2] = v.z; Ws[wk][wc + 3] = v.w;
        }
        __syncthreads();
        #pragma unroll 4
        for (int kk = 0; kk < 16; ++kk) {
            float4 a4 = *reinterpret_cast<const float4*>(&As[kk][ty4]);
            float4 b4 = *reinterpret_cast<const float4*>(&Ws[kk][tx4]);
            float a[4] = {a4.x, a4.y, a4.z, a4.w};
            float b[4] = {b4.x, b4.y, b4.z, b4.w};
            #pragma unroll
            for (int i = 0; i < 4; ++i)
                #pragma unroll
                for (int j = 0; j < 4; ++j) acc[i][j] += a[i] * b[j];
        }
        __syncthreads();
    }
    #pragma unroll
    for (int i = 0; i < 4; ++i) {
        int r = row0 + ty4 + i;
        if (r >= M) continue;
        #pragma unroll
        for (int j = 0; j < 4; ++j) {
            int c = col0 + tx4 + j;
            if (c >= Ncols) continue;
            float v = acc[i][j];
            if (bias) v += bias[c];
            if (ACT == 1) v = fast_tanh(v);
            else if (ACT == 2) v = fmaxf(v, 0.f);
            C[(size_t)r * ldc + c] = v;
        }
    }
}

// ------------------------------------------------- LSTM: split-K GEMM + gates
__global__ __launch_bounds__(256) void lstm_gemm_kernel(
    const float* __restrict__ h, const float* __restrict__ rk, float* __restrict__ zgp) {
    __shared__ float As[16][68];
    __shared__ float Ws[16][68];
    const int tid = threadIdx.x;
    const int tx4 = (tid & 15) * 4, ty4 = (tid >> 4) * 4;
    const int col0 = blockIdx.x * 64, row0 = blockIdx.y * 64, kb = blockIdx.z * 256;
    const int am = tid >> 2, ak = (tid & 3) * 4;
    const int wk = tid >> 4, wc = (tid & 15) * 4;
    float acc[4][4] = {};
    for (int k0 = kb; k0 < kb + 256; k0 += 16) {
        {
            float4 v = *reinterpret_cast<const float4*>(h + (size_t)(row0 + am) * Hd + k0 + ak);
            As[ak + 0][am] = v.x; As[ak + 1][am] = v.y; As[ak + 2][am] = v.z; As[ak + 3][am] = v.w;
        }
        {
            *reinterpret_cast<float4*>(&Ws[wk][wc]) =
                *reinterpret_cast<const float4*>(rk + (size_t)(k0 + wk) * H4 + col0 + wc);
        }
        __syncthreads();
        #pragma unroll 4
        for (int kk = 0; kk < 16; ++kk) {
            float4 a4 = *reinterpret_cast<const float4*>(&As[kk][ty4]);
            float4 b4 = *reinterpret_cast<const float4*>(&Ws[kk][tx4]);
            float a[4] = {a4.x, a4.y, a4.z, a4.w};
            float b[4] = {b4.x, b4.y, b4.z, b4.w};
            #pragma unroll
            for (int i = 0; i < 4; ++i)
                #pragma unroll
                for (int j = 0; j < 4; ++j) acc[i][j] += a[i] * b[j];
        }
        __syncthreads();
    }
    float* dst = zgp + (size_t)blockIdx.z * (Bq * H4);
    #pragma unroll
    for (int i = 0; i < 4; ++i) {
        int r = row0 + ty4 + i;
        *reinterpret_cast<float4*>(dst + (size_t)r * H4 + col0 + tx4) =
            make_float4(acc[i][0], acc[i][1], acc[i][2], acc[i][3]);
    }
}

__global__ __launch_bounds__(256) void lstm_gates_kernel(
    const float* __restrict__ zgp, const float* __restrict__ xp,
    float* __restrict__ c, float* __restrict__ h, short* __restrict__ sent2, int t) {
    int i = blockIdx.x * 256 + threadIdx.x;  // B*H
    int b = i >> 9, hh = i & 511;
    const float* xr = xp + ((size_t)b * Tseq + t) * H4;
    float z[4];
    #pragma unroll
    for (int g = 0; g < 4; ++g) {
        float s = xr[g * 512 + hh];
        #pragma unroll
        for (int kc = 0; kc < 2; ++kc)
            s += zgp[(size_t)kc * (Bq * H4) + (size_t)b * H4 + g * 512 + hh];
        z[g] = s;
    }
    float ig = fast_sigmoid(z[0]);
    float fg = fast_sigmoid(z[1]);
    float gg = fast_tanh(z[2]);
    float og = fast_sigmoid(z[3]);
    float cv = fg * c[i] + ig * gg;
    c[i] = cv;
    float hv = og * fast_tanh(cv);
    h[i] = hv;
    short hb = f2bf(hv), lb = f2bf(hv - bf2f(hb));
    sent2[((size_t)b * Tseq + t) * 1024 + hh] = hb;
    sent2[((size_t)b * Tseq + t) * 1024 + 512 + hh] = lb;
}

// ---- fused qlog for all 3 calls; 2 h-chunks of 256, 2 h per thread
__global__ __launch_bounds__(256) void qlog3_kernel(
    const float* __restrict__ wm0, const float* __restrict__ wm1, const float* __restrict__ wm2,
    const float* __restrict__ Ie, const float* __restrict__ qe0, const float* __restrict__ qe1,
    const float* __restrict__ qe2, const float* __restrict__ wqa, float* __restrict__ qlogp) {
    const int b = blockIdx.x, chunk = blockIdx.y;   // chunk in {0,1}
    __shared__ float wms[3][Tseq][Nimg];
    __shared__ float red[4][40];
    const int tid = threadIdx.x;
    const float* wsrc[3] = {wm0, wm1, wm2};
    for (int e = tid; e < 3 * 1274; e += 256) {
        int c = e / 1274, r = e % 1274;
        *reinterpret_cast<float4*>(&wms[c][0][0] + 4 * r) =
            *reinterpret_cast<const float4*>(wsrc[c] + (size_t)b * (Tseq * Nimg) + 4 * r);
    }
    __syncthreads();
    const int hl = tid & 127, thalf = tid >> 7, tt0 = thalf * 13;
    const int h1 = chunk * 256 + hl, h2 = h1 + 128;
    float acc[3][13][2] = {};
    const float* iep1 = Ie + (size_t)b * Nimg * Hd + h1;
    const float* iep2 = Ie + (size_t)b * Nimg * Hd + h2;
    for (int n4 = 0; n4 < 49; ++n4) {
        float ieA0 = iep1[(size_t)(4 * n4 + 0) * Hd];
        float ieA1 = iep1[(size_t)(4 * n4 + 1) * Hd];
        float ieA2 = iep1[(size_t)(4 * n4 + 2) * Hd];
        float ieA3 = iep1[(size_t)(4 * n4 + 3) * Hd];
        float ieB0 = iep2[(size_t)(4 * n4 + 0) * Hd];
        float ieB1 = iep2[(size_t)(4 * n4 + 1) * Hd];
        float ieB2 = iep2[(size_t)(4 * n4 + 2) * Hd];
        float ieB3 = iep2[(size_t)(4 * n4 + 3) * Hd];
        #pragma unroll
        for (int c = 0; c < 3; ++c)
            #pragma unroll
            for (int tt = 0; tt < 13; ++tt) {
                float4 w4 = *reinterpret_cast<const float4*>(&wms[c][tt0 + tt][4 * n4]);
                acc[c][tt][0] += w4.x * ieA0 + w4.y * ieA1 + w4.z * ieA2 + w4.w * ieA3;
                acc[c][tt][1] += w4.x * ieB0 + w4.y * ieB1 + w4.z * ieB2 + w4.w * ieB3;
            }
    }
    const float wq1 = wqa[h1], wq2 = wqa[h2];
    const int lane = tid & 63, w = tid >> 6;
    const float* qes[3] = {qe0, qe1, qe2};
    #pragma unroll
    for (int c = 0; c < 3; ++c)
        #pragma unroll
        for (int tt = 0; tt < 13; ++tt) {
            int t = tt0 + tt;
            const float* qrow = qes[c] + ((size_t)(b * 26 + t)) * Hd;
            float v = fast_tanh(acc[c][tt][0] + qrow[h1]) * wq1 +
                      fast_tanh(acc[c][tt][1] + qrow[h2]) * wq2;
            #pragma unroll
            for (int off = 32; off; off >>= 1) v += __shfl_xor(v, off);
            if (lane == 0) red[w][c * 13 + tt] = v;
        }
    __syncthreads();
    if (tid < 39) {
        int c = tid / 13, tt = tid % 13;
        qlogp[((size_t)c * Bq + b) * (2 * 26) + chunk * 26 + tt] = red[0][tid] + red[1][tid];
    } else if (tid >= 64 && tid < 103) {
        int id = tid - 64;
        int c = id / 13, tt = id % 13;
        qlogp[((size_t)c * Bq + b) * (2 * 26) + chunk * 26 + 13 + tt] = red[2][id] + red[3][id];
    }
}

// ---- ilog, h-split x2: grid (Bq, 4, 3); t-outer in TWO register-sized passes (<=4 groups each)
__global__ __launch_bounds__(256) void ilog3_kernel(
    const float* __restrict__ wmb, const float* __restrict__ qeb,
    const float* __restrict__ Ie, const float* __restrict__ wia,
    float* __restrict__ ilogp) {
    const int b = blockIdx.x, lvl = blockIdx.z;
    const int nbase = (blockIdx.y & 1) * 98, hc = blockIdx.y >> 1;
    const int hbase = hc * 256;
    const float* wm = wmb + (size_t)lvl * Bq * Tseq * Nimg;
    const float* qe = qeb + (size_t)lvl * Bq * Tseq * Hd;
    float* ilog = ilogp + (size_t)hc * (3 * Bq * Nimg) + (size_t)lvl * Bq * Nimg;
    __shared__ float qes[Tseq][260];
    __shared__ __align__(16) float wms[Tseq][104];
    const int tid = threadIdx.x;
    for (int e = tid; e < Tseq * 64; e += 256) {
        int t = e >> 6, q4 = (e & 63) * 4;
        *reinterpret_cast<float4*>(&qes[t][q4]) =
            *reinterpret_cast<const float4*>(qe + ((size_t)(b * 26 + t)) * Hd + hbase + q4);
    }
    for (int e = tid; e < Tseq * 100; e += 256) {
        int t = e / 100, n = e % 100;
        wms[t][n] = (n < 98 && nbase + n < Nimg)
                    ? wm[((size_t)(b * 26 + t)) * Nimg + nbase + n] : 0.f;
    }
    __syncthreads();
    const int lane = tid & 63, w = tid >> 6;
    const int nw0 = w * 4;
    float4 wi = *reinterpret_cast<const float4*>(wia + hbase + 4 * lane);
    // one pass over t with NG (<=4) accumulator groups starting at group gbeg
    auto PASS = [&](int gbeg, int NG) {
        float4 acc[4][4];
        #pragma unroll
        for (int g = 0; g < 4; ++g)
            #pragma unroll
            for (int i = 0; i < 4; ++i) acc[g][i] = make_float4(0.f, 0.f, 0.f, 0.f);
        for (int t = 0; t < Tseq; ++t) {
            float4 q0 = *reinterpret_cast<const float4*>(&qes[t][4 * lane]);
            #pragma unroll
            for (int g = 0; g < 4; ++g) {
                if (g >= NG) continue;
                int n0 = nw0 + (gbeg + g) * 16;
                if (n0 < 98) {
                    float4 wv = *reinterpret_cast<const float4*>(&wms[t][n0]);
                    float wvv[4] = {wv.x, wv.y, wv.z, wv.w};
                    #pragma unroll
                    for (int i = 0; i < 4; ++i) {
                        acc[g][i].x += wvv[i] * q0.x; acc[g][i].y += wvv[i] * q0.y;
                        acc[g][i].z += wvv[i] * q0.z; acc[g][i].w += wvv[i] * q0.w;
                    }
                }
            }
        }
        #pragma unroll
        for (int g = 0; g < 4; ++g) {
            if (g >= NG) continue;
            int n0 = nw0 + (gbeg + g) * 16;
            if (n0 >= 98) continue;
            #pragma unroll
            for (int i = 0; i < 4; ++i) {
                int n = n0 + i;
                if (n >= 98 || nbase + n >= Nimg) continue;
                const float* iebn = Ie + ((size_t)(b * Nimg) + nbase + n) * Hd + hbase;
                float4 e0 = *reinterpret_cast<const float4*>(iebn + 4 * lane);
                float v = fast_tanh(acc[g][i].x + e0.x) * wi.x +
                          fast_tanh(acc[g][i].y + e0.y) * wi.y +
                          fast_tanh(acc[g][i].z + e0.z) * wi.z +
                          fast_tanh(acc[g][i].w + e0.w) * wi.w;
                #pragma unroll
                for (int off = 32; off; off >>= 1) v += __shfl_xor(v, off);
                if (lane == 0) ilog[(size_t)b * Nimg + nbase + n] = v;
            }
        }
    };
    PASS(0, 4);
    PASS(4, 3);
}

// ---------------------------------------------------------------- softmaxes
// grid (Bq, 3)
__global__ void softmaxT_part_kernel(const float* __restrict__ lgp, float* __restrict__ att) {
    int b = blockIdx.x, c = blockIdx.y, lane = threadIdx.x;  // block 64
    float v = -INFINITY;
    if (lane < Tseq) {
        const float* p = lgp + ((size_t)c * Bq + b) * (2 * 26) + lane;
        v = p[0] + p[26];
    }
    float m = v;
    #pragma unroll
    for (int off = 32; off; off >>= 1) m = fmaxf(m, __shfl_xor(m, off));
    float e = (lane < Tseq) ? __expf(v - m) : 0.f;
    float s = e;
    #pragma unroll
    for (int off = 32; off; off >>= 1) s += __shfl_xor(s, off);
    if (lane < Tseq) att[((size_t)c * Bq + b) * Tseq + lane] = e / s;
}

// grid (Bq, 3); sums the two h-half partials while loading
__global__ void softmax_N_kernel(const float* __restrict__ lg, float* __restrict__ att) {
    int b = blockIdx.x, c = blockIdx.y, lane = threadIdx.x;  // block 64
    const float* lb0 = lg + ((size_t)c * Bq + b) * Nimg;
    const float* lb1 = lb0 + (size_t)3 * Bq * Nimg;
    float* ab = att + ((size_t)c * Bq + b) * Nimg;
    float v[4]; float m = -INFINITY;
    #pragma unroll
    for (int k = 0; k < 4; ++k) {
        int n = lane + 64 * k;
        v[k] = (n < Nimg) ? (lb0[n] + lb1[n]) : -INFINITY;
        m = fmaxf(m, v[k]);
    }
    #pragma unroll
    for (int off = 32; off; off >>= 1) m = fmaxf(m, __shfl_xor(m, off));
    float e[4]; float s = 0.f;
    #pragma unroll
    for (int k = 0; k < 4; ++k) {
        int n = lane + 64 * k;
        e[k] = (n < Nimg) ? __expf(v[k] - m) : 0.f;
        s += e[k];
    }
    #pragma unroll
    for (int off = 32; off; off >>= 1) s += __shfl_xor(s, off);
    #pragma unroll
    for (int k = 0; k < 4; ++k) {
        int n = lane + 64 * k;
        if (n < Nimg) ab[n] = e[k] / s;
    }
}

// ---- fused feature pooling for all 3 calls (split-bf16 inputs reconstructed)
__global__ __launch_bounds__(256) void feat3_kernel(
    const float* __restrict__ qatt0, const float* __restrict__ qatt1, const float* __restrict__ qatt2,
    const float* __restrict__ iatt0, const float* __restrict__ iatt1, const float* __restrict__ iatt2,
    const short* __restrict__ Qw2, const short* __restrict__ Qp2, const short* __restrict__ Qs2,
    const short* __restrict__ img2, float* __restrict__ s_part) {
    const int b = blockIdx.x, chunk = blockIdx.y, tid = threadIdx.x;
    float a[3][2] = {};
    if (chunk == 0) {
        for (int t = 0; t < Tseq; ++t) {
            float w0 = qatt0[b * Tseq + t], w1 = qatt1[b * Tseq + t], w2 = qatt2[b * Tseq + t];
            const short* p0 = Qw2 + ((size_t)(b * Tseq + t)) * 1024;
            const short* p1 = Qp2 + ((size_t)(b * Tseq + t)) * 1024;
            const short* p2 = Qs2 + ((size_t)(b * Tseq + t)) * 1024;
            a[0][0] += w0 * (bf2f(p0[tid]) + bf2f(p0[512 + tid]));
            a[0][1] += w0 * (bf2f(p0[256 + tid]) + bf2f(p0[768 + tid]));
            a[1][0] += w1 * (bf2f(p1[tid]) + bf2f(p1[512 + tid]));
            a[1][1] += w1 * (bf2f(p1[256 + tid]) + bf2f(p1[768 + tid]));
            a[2][0] += w2 * (bf2f(p2[tid]) + bf2f(p2[512 + tid]));
            a[2][1] += w2 * (bf2f(p2[256 + tid]) + bf2f(p2[768 + tid]));
        }
    }
    int ns, ne;
    if (chunk == 0)      { ns = 0;   ne = 30;  }
    else if (chunk == 1) { ns = 30;  ne = 86;  }
    else if (chunk == 2) { ns = 86;  ne = 141; }
    else                 { ns = 141; ne = 196; }
    for (int n = ns; n < ne; ++n) {
        float w0 = iatt0[b * Nimg + n], w1 = iatt1[b * Nimg + n], w2 = iatt2[b * Nimg + n];
        const short* p = img2 + ((size_t)(b * Nimg) + n) * 1024;
        float v0 = bf2f(p[tid]) + bf2f(p[512 + tid]);
        float v1 = bf2f(p[256 + tid]) + bf2f(p[768 + tid]);
        a[0][0] += w0 * v0; a[0][1] += w0 * v1;
        a[1][0] += w1 * v0; a[1][1] += w1 * v1;
        a[2][0] += w2 * v0; a[2][1] += w2 * v1;
    }
    #pragma unroll
    for (int c = 0; c < 3; ++c) {
        float* dst = s_part + ((size_t)(chunk * 3 + c) * Bq + b) * Hd;
        dst[tid] = a[c][0];
        dst[tid + 256] = a[c][1];
    }
}

__global__ void feat_combine_kernel(const float* __restrict__ s_part, float* __restrict__ s0,
                                    float* __restrict__ s1, float* __restrict__ s2) {
    int i = blockIdx.x * 256 + threadIdx.x;  // over 3*Bq*Hd
    int c = i / (Bq * Hd), r = i % (Bq * Hd);
    float v = 0.f;
    #pragma unroll
    for (int ch = 0; ch < 4; ++ch) v += s_part[(size_t)(ch * 3 + c) * (Bq * Hd) + r];
    float* dst = (c == 0) ? s0 : (c == 1) ? s1 : s2;
    dst[r] = v;
}

__global__ void concat_kernel(const float* __restrict__ x, const float* __restrict__ y,
                              float* __restrict__ out) {
    int i = blockIdx.x * 256 + threadIdx.x;  // over B*512
    int b = i >> 9, j = i & 511;
    out[(size_t)b * 1024 + j] = x[i];
    out[(size_t)b * 1024 + 512 + j] = y[i];
}

__global__ __launch_bounds__(256) void softmax_C_kernel(const float* __restrict__ lg,
                                                        float* __restrict__ out) {
    int b = blockIdx.x, tid = threadIdx.x;
    __shared__ float red[4];
    const float* lb = lg + (size_t)b * Ccls;
    float v[4]; float m = -INFINITY;
    #pragma unroll
    for (int k = 0; k < 4; ++k) {
        int j = tid + 256 * k;
        v[k] = (j < Ccls) ? lb[j] : -INFINITY;
        m = fmaxf(m, v[k]);
    }
    #pragma unroll
    for (int off = 32; off; off >>= 1) m = fmaxf(m, __shfl_xor(m, off));
    int lane = tid & 63, w = tid >> 6;
    if (lane == 0) red[w] = m;
    __syncthreads();
    m = fmaxf(fmaxf(red[0], red[1]), fmaxf(red[2], red[3]));
    __syncthreads();
    float e[4]; float s = 0.f;
    #pragma unroll
    for (int k = 0; k < 4; ++k) {
        int j = tid + 256 * k;
        e[k] = (j < Ccls) ? __expf(v[k] - m) : 0.f;
        s += e[k];
    }
    #pragma unroll
    for (int off = 32; off; off >>= 1) s += __shfl_xor(s, off);
    if (lane == 0) red[w] = s;
    __syncthreads();
    s = red[0] + red[1] + red[2] + red[3];
    float inv = 1.f / s;
    #pragma unroll
    for (int k = 0; k < 4; ++k) {
        int j = tid + 256 * k;
        if (j < Ccls) out[(size_t)b * Ccls + j] = e[k] * inv;
    }
}

// =============================================================== orchestration
extern "C" void kernel_launch(void* const* d_in, const int* in_sizes, int n_in,
                              void* d_out, int out_size, void* d_ws, size_t ws_size,
                              hipStream_t stream) {
    const float* image   = (const float*)d_in[0];
    const int*   question= (const int*)  d_in[1];
    const float* embed   = (const float*)d_in[2];
    const float* W_img   = (const float*)d_in[3];
    const float* b_img   = (const float*)d_in[4];
    const float* W_uni   = (const float*)d_in[5];
    const float* b_uni   = (const float*)d_in[6];
    const float* W_bi    = (const float*)d_in[7];
    const float* b_bi    = (const float*)d_in[8];
    const float* W_tri   = (const float*)d_in[9];
    const float* b_tri   = (const float*)d_in[10];
    const float* lstm_k  = (const float*)d_in[11];
    const float* lstm_rk = (const float*)d_in[12];
    const float* lstm_b  = (const float*)d_in[13];
    const float* W_corr  = (const float*)d_in[14];
    const float* b_corr  = (const float*)d_in[15];
    const float* W_qe    = (const float*)d_in[16];
    const float* b_qe    = (const float*)d_in[17];
    const float* W_ie    = (const float*)d_in[18];
    const float* b_ie    = (const float*)d_in[19];
    const float* w_qa    = (const float*)d_in[20];
    const float* w_ia    = (const float*)d_in[22];
    const float* W_w     = (const float*)d_in[24];
    const float* b_w     = (const float*)d_in[25];
    const float* W_p     = (const float*)d_in[26];
    const float* b_p     = (const float*)d_in[27];
    const float* W_s     = (const float*)d_in[28];
    const float* b_s     = (const float*)d_in[29];
    const float* W_fc1   = (const float*)d_in[30];
    const float* b_fc1   = (const float*)d_in[31];
    const float* W_fc    = (const float*)d_in[32];
    const float* b_fc    = (const float*)d_in[33];

    float* p = (float*)d_ws;
    size_t off = 0;
    auto take = [&](size_t n) { float* r = p + off; off += n; return r; };
    auto take_s = [&](size_t n) { short* r = (short*)(p + off); off += n / 2; return r; };
    float* bufB   = take((size_t)Bq * Nimg * Hd);   // image2 -> Y -> img_embed
    float* xp     = take((size_t)Bq * Tseq * H4);   // xp, then qe0-2 + s_part tail
    float* wm0    = take((size_t)Bq * Tseq * Nimg); // later: catb/fc1b/logits
    float* wm1    = take((size_t)Bq * Tseq * Nimg); // later: s0-2/hw/hp/hsv
    float* wm2    = take((size_t)Bq * Tseq * Nimg);
    float* hbuf   = take((size_t)Bq * Hd);
    float* cbuf   = take((size_t)Bq * Hd);
    float* zgp    = take((size_t)2 * Bq * H4);
    float* qlogp  = take((size_t)3 * Bq * 4 * Tseq);
    float* qatt0  = take((size_t)Bq * Tseq);
    float* qatt1  = take((size_t)Bq * Tseq);
    float* qatt2  = take((size_t)Bq * Tseq);
    float* ilogp  = take((size_t)2 * 3 * Bq * Nimg);
    float* iatt0  = take((size_t)Bq * Nimg);
    float* iatt1  = take((size_t)Bq * Nimg);
    float* iatt2  = take((size_t)Bq * Nimg);
    float* qb     = take((size_t)MT3);
    // split-bf16 buffers
    short* imgS2   = take_s((size_t)Bq * Nimg * 1024);   // img2 (GEMM-2 output)
    short* words2  = take_s((size_t)Bq * Tseq * 1024);
    short* phrase2 = take_s((size_t)Bq * Tseq * 1024);
    short* sentn2  = take_s((size_t)Bq * Tseq * 1024);
    short* Qc2     = take_s((size_t)MT3 * 1024);         // DEDICATED (enables Qcqe||ie batch)
    short* WimgT2  = take_s((size_t)Hd * KP);
    short* WieT2   = take_s((size_t)Hd * KP);
    short* WcorrR2 = take_s((size_t)Hd * KP);            // adjacent pair: [WcorrR2 | WqeT2]
    short* WqeT2   = take_s((size_t)Hd * KP);            // = WcorrR2 + 512*KP (1024-row B)
    short* WconvT2 = take_s((size_t)6 * Hd * KP);        // 3072 rows
    short* lkT2    = take_s((size_t)H4 * KP);            // 2048 rows

    float* qe0 = xp;                                // xp dead after LSTM
    float* qe1 = xp + (size_t)Bq * Tseq * Hd;
    float* qe2 = xp + 2 * (size_t)Bq * Tseq * Hd;
    float* s_part = xp + 3 * (size_t)Bq * Tseq * Hd;          // 12*Bq*Hd fits tail
    float* Y      = bufB;                                      // conv tap outputs
    short* image2 = (short*)bufB;                              // input split (dead before Y)
    float* catb   = wm0;                                       // wm0 dead after step 11
    float* fc1b   = wm0 + (size_t)Bq * 2 * Hd;
    float* logits = wm0 + 2 * (size_t)Bq * 2 * Hd;
    float* s0     = wm1;                                       // wm1 dead after step 11
    float* s1     = wm1 + 1 * (size_t)Bq * Hd;
    float* s2     = wm1 + 2 * (size_t)Bq * Hd;
    float* hw     = wm1 + 3 * (size_t)Bq * Hd;
    float* hp     = wm1 + 4 * (size_t)Bq * Hd;
    float* hsv    = wm1 + 5 * (size_t)Bq * Hd;

    const int MI = Bq * Nimg;   // 50176
    const int MT = Bq * Tseq;   // 6656

    // 0. ALL weight splits in one launch (z==1: W_corr rows for Qc)
    wsplit_all_kernel<<<dim3(8, 8, 14), 256, 0, stream>>>(
        W_img, W_corr, W_ie, W_qe, W_uni, W_bi, W_tri, lstm_k,
        WimgT2, WcorrR2, WieT2, WqeT2, WconvT2, lkT2);

    // 1. word embeddings (split only)
    embed_kernel<<<MT, 128, 0, stream>>>(question, embed, words2);
    // 2. split image into bufB bytes, then img2 = split(tanh(image @ W_img + b))
    split_kernel<<<MI / 2, 256, 0, stream>>>(image, image2);
    mfma_gemm8_kernel<1, 1><<<dim3((MI / 256) * (Hd / 256)), 512, 0, stream>>>(
        image2, WimgT2, b_img, nullptr, imgS2, MI, Hd);
    // 3. conv taps as one GEMM into bufB (image2 dead now) + shifted combine
    mfma_gemm8_kernel<0, 0><<<dim3((MT / 256) * (3072 / 256)), 512, 0, stream>>>(
        words2, WconvT2, nullptr, Y, nullptr, MT, 3072);
    conv_combine_kernel<<<(MT * Hd) / 256, 256, 0, stream>>>(Y, b_uni, b_bi, b_tri, phrase2);
    // 4. xp = phrase @ lstm_k + lstm_b
    mfma_gemm8_kernel<0, 0><<<dim3((MT / 256) * (H4 / 256)), 512, 0, stream>>>(
        phrase2, lkT2, lstm_b, xp, nullptr, MT, H4);
    // 5. LSTM (fp32 split-K GEMM + fused combine/gates; sentn written split)
    hipMemsetAsync(hbuf, 0, (size_t)Bq * Hd * sizeof(float), stream);
    hipMemsetAsync(cbuf, 0, (size_t)Bq * Hd * sizeof(float), stream);
    for (int t = 0; t < Tseq; ++t) {
        lstm_gemm_kernel<<<dim3(32, 4, 2), 256, 0, stream>>>(hbuf, lstm_rk, zgp);
        lstm_gates_kernel<<<(Bq * Hd) / 256, 256, 0, stream>>>(zgp, xp, cbuf, hbuf, sentn2, t);
    }
    // 6. qb; then ONE batched dispatch: seg0 = [Qc|qe] (MT3 x 1024, OUT=2),
    //    seg1 = img_embed (MI x 512 -> bufB fp32 + b_ie). Y dead; xp (qe0 alias) dead.
    qb_kernel<<<MT3 / 4, 256, 0, stream>>>(words2, b_corr, qb);
    {
        const int nwg0 = (MT3 / 256) * (1024 / 256);   // 312
        const int nwg1 = (MI / 256) * (Hd / 256);      // 392
        mfma_gemm8_dual_kernel<<<dim3(nwg0 + nwg1), 512, 0, stream>>>(
            words2, WcorrR2, b_qe, qe0, Qc2, MT3, 1024, nwg0,
            imgS2, WieT2, b_ie, bufB, MI, Hd);
    }
    // 7. fused affinity maps: wm = tanh(Qc . img^T + qb)
    wm3_mfma_kernel<<<dim3(2, Bq), 256, 0, stream>>>(Qc2, imgS2, qb, wm0, wm1, wm2);
    // 10. fused qlog (all 3 calls) + merged question softmaxes
    qlog3_kernel<<<dim3(Bq, 2), 256, 0, stream>>>(wm0, wm1, wm2, bufB, qe0, qe1, qe2, w_qa, qlogp);
    softmaxT_part_kernel<<<dim3(Bq, 3), 64, 0, stream>>>(qlogp, qatt0);
    // 11. merged ilog (3 levels, h-split, t-outer 2-pass regs) + merged image softmaxes
    ilog3_kernel<<<dim3(Bq, 4, 3), 256, 0, stream>>>(wm0, qe0, bufB, w_ia, ilogp);
    softmax_N_kernel<<<dim3(Bq, 3), 64, 0, stream>>>(ilogp, iatt0);
    // 12. fused feature pooling (wm0/wm1 now reusable)
    feat3_kernel<<<dim3(Bq, 4), 256, 0, stream>>>(qatt0, qatt1, qatt2, iatt0, iatt1, iatt2,
                                                  words2, phrase2, sentn2, imgS2, s_part);
    feat_combine_kernel<<<(3 * Bq * Hd) / 256, 256, 0, stream>>>(s_part, s0, s1, s2);
    // 13. head (fp32)
    gemm_kernel<1><<<dim3(Hd / 64, Bq / 64), 256, 0, stream>>>(
        s0, Hd, W_w, Hd, b_w, hw, Hd, Bq, Hd, Hd);
    concat_kernel<<<(Bq * Hd) / 256, 256, 0, stream>>>(s1, hw, catb);
    gemm_kernel<1><<<dim3(Hd / 64, Bq / 64), 256, 0, stream>>>(
        catb, 2 * Hd, W_p, Hd, b_p, hp, Hd, Bq, Hd, 2 * Hd);
    concat_kernel<<<(Bq * Hd) / 256, 256, 0, stream>>>(s2, hp, catb);
    gemm_kernel<1><<<dim3(Hd / 64, Bq / 64), 256, 0, stream>>>(
        catb, 2 * Hd, W_s, Hd, b_s, hsv, Hd, Bq, Hd, 2 * Hd);
    gemm_kernel<2><<<dim3((2 * Hd) / 64, Bq / 64), 256, 0, stream>>>(
        hsv, Hd, W_fc1, 2 * Hd, b_fc1, fc1b, 2 * Hd, Bq, 2 * Hd, Hd);
    gemm_kernel<0><<<dim3((Ccls + 63) / 64, Bq / 64), 256, 0, stream>>>(
        fc1b, 2 * Hd, W_fc, Ccls, b_fc, logits, Ccls, Bq, Ccls, 2 * Hd);
    softmax_C_kernel<<<Bq, 256, 0, stream>>>(logits, (float*)d_out);
}